// Round 11
// baseline (45731.531 us; speedup 1.0000x reference)
//
#include <hip/hip_runtime.h>
#include <math.h>

// ---------------------------------------------------------------------------
// GOTSim: GCN features -> reduced 384x384 LAP (exact JV: col-reduction +
// fused greedy/u-init + augmenting row reduction + MULTI-SOURCE shortest
// augmenting path with PER-PHASE free-column dual refresh).
// Key fix vs R10: v[j] = min_i(C_ij - u_i) is recomputed for all remaining
// free columns at the START of every phase (tolls reopen after each dual
// update otherwise) -> with all free rows as d=0 sources, phases terminate
// after ~1 pop round. Refresh only RAISES v of free columns to exact
// tightness (fmin of identical exprs) -> dual-feasible, exact.
// LAP_768(block) = Sum(D)+Sum(I) + LAP_384(min(0, M_ij - D_i - I_j)).
// ---------------------------------------------------------------------------

namespace {
constexpr int kN   = 384;   // nodes per graph == reduced LAP dimension
constexpr int kNN  = 768;   // original LAP dimension (for normalization)
constexpr int kE   = 3072;  // edges per graph
constexpr float kInf = 1e30f;
}

// ---- wave64 reductions via DPP (row_shr 1,2,4,8 + row_bcast 15,31) --------
__device__ __forceinline__ float wave_min_bcast(float xv) {
    float v = xv;
    #define MSTAGE(ctrl) { int t = __builtin_amdgcn_update_dpp(__float_as_int(v), __float_as_int(v), ctrl, 0xF, 0xF, false); v = fminf(v, __int_as_float(t)); }
    MSTAGE(0x111); MSTAGE(0x112); MSTAGE(0x114); MSTAGE(0x118); MSTAGE(0x142); MSTAGE(0x143);
    #undef MSTAGE
    return __int_as_float(__builtin_amdgcn_readlane(__float_as_int(v), 63));
}

// (min, second-min): disabled lanes contribute identity (+inf) via old=INF.
__device__ __forceinline__ void wave_min2_bcast(float m1, float m2, float& w1, float& w2) {
    const int INFB = __float_as_int(kInf);
    #define M2STAGE(ctrl) { \
        int t1 = __builtin_amdgcn_update_dpp(INFB, __float_as_int(m1), ctrl, 0xF, 0xF, false); \
        int t2 = __builtin_amdgcn_update_dpp(INFB, __float_as_int(m2), ctrl, 0xF, 0xF, false); \
        float o1 = __int_as_float(t1); float o2 = __int_as_float(t2); \
        float n2 = fminf(fmaxf(m1, o1), fminf(m2, o2)); \
        m1 = fminf(m1, o1); m2 = n2; }
    M2STAGE(0x111); M2STAGE(0x112); M2STAGE(0x114); M2STAGE(0x118); M2STAGE(0x142); M2STAGE(0x143);
    #undef M2STAGE
    w1 = __int_as_float(__builtin_amdgcn_readlane(__float_as_int(m1), 63));
    w2 = __int_as_float(__builtin_amdgcn_readlane(__float_as_int(m2), 63));
}

// ---- degree / dinv --------------------------------------------------------

__global__ void init_deg(float* deg1, float* deg2) {
    int v = blockIdx.x * blockDim.x + threadIdx.x;
    if (v < kN) { deg1[v] = 1.0f; deg2[v] = 1.0f; }
}

__global__ void scatter_deg(const int* ei1, const int* ei2, float* deg1, float* deg2) {
    int e = blockIdx.x * blockDim.x + threadIdx.x;
    if (e < kE) {
        atomicAdd(&deg1[ei1[kE + e]], 1.0f);
    } else if (e < 2 * kE) {
        atomicAdd(&deg2[ei2[kE + (e - kE)]], 1.0f);
    }
}

__global__ void deg_to_dinv(float* deg1, float* deg2) {
    int v = blockIdx.x * blockDim.x + threadIdx.x;
    if (v < kN) { deg1[v] = rsqrtf(deg1[v]); deg2[v] = rsqrtf(deg2[v]); }
}

// ---- GCN layer ------------------------------------------------------------

__global__ void gemm_act(const float* __restrict__ x, const float* __restrict__ w,
                         float* __restrict__ h, int FIN, int FOUT, int relu) {
    int idx = blockIdx.x * blockDim.x + threadIdx.x;
    if (idx >= kN * FOUT) return;
    int row = idx / FOUT;
    int oc  = idx - row * FOUT;
    float acc = 0.0f;
    for (int k = 0; k < FIN; ++k) {
        float xv = x[row * FIN + k];
        if (relu) xv = fmaxf(xv, 0.0f);
        acc += xv * w[k * FOUT + oc];
    }
    h[idx] = acc;
}

__global__ void agg_init(const float* __restrict__ h, const float* __restrict__ dinv,
                         const float* __restrict__ b, float* __restrict__ out, int F) {
    int idx = blockIdx.x * blockDim.x + threadIdx.x;
    if (idx >= kN * F) return;
    int v = idx / F;
    int f = idx - v * F;
    float dv = dinv[v];
    out[idx] = b[f] + dv * dv * h[idx];
}

__global__ void agg_edges(const int* __restrict__ ei, const float* __restrict__ h,
                          const float* __restrict__ dinv, float* __restrict__ out, int F) {
    int idx = blockIdx.x * blockDim.x + threadIdx.x;
    if (idx >= kE * F) return;
    int e = idx / F;
    int f = idx - e * F;
    int s = ei[e];
    int d = ei[kE + e];
    atomicAdd(&out[d * F + f], dinv[s] * dinv[d] * h[s * F + f]);
}

// ---- diag terms -----------------------------------------------------------

__global__ void node_dots(const float* __restrict__ f, const float* __restrict__ p,
                          float* __restrict__ out, int F) {
    int i = blockIdx.x * blockDim.x + threadIdx.x;
    if (i >= kN) return;
    float acc = 0.0f;
    for (int k = 0; k < F; ++k) acc += f[i * F + k] * p[k];
    out[i] = -acc;
}

// ---- reduced cost matrix (+ optional transpose) + column minima -----------
// Entries <= 0 so uint bits are order-reversed: atomicMax == float min.

__global__ void build_cost_red(const float* __restrict__ f1, const float* __restrict__ f2,
                               const float* __restrict__ D, const float* __restrict__ I,
                               float* __restrict__ C, float* __restrict__ CT, int have_ct,
                               unsigned* __restrict__ vbits, int F) {
    int j = blockIdx.x * blockDim.x + threadIdx.x;
    int i = blockIdx.y;
    if (j >= kN) return;
    float acc = 0.0f;
    for (int k = 0; k < F; ++k) acc += f1[i * F + k] * f2[j * F + k];
    float val = (-acc) - D[i] - I[j];
    float c = fminf(0.0f, val);
    C[i * kN + j] = c;
    if (have_ct) CT[(size_t)j * kN + i] = c;
    atomicMax(&vbits[j], __float_as_uint(c));
}

// ---- 384x384 exact JV LAP, one wave per matrix ----------------------------

__global__ __launch_bounds__(64) void lap384(const float* __restrict__ Call,
                                             const float* __restrict__ CTall, int have_ct,
                                             const unsigned* __restrict__ vbits_all,
                                             const float* __restrict__ Dall,
                                             const float* __restrict__ Iall,
                                             float* __restrict__ loss_out) {
    const int m = blockIdx.x;
    const float* C  = Call  + (size_t)m * kN * kN;
    const float* CT = CTall + (size_t)m * kN * kN;
    const unsigned* vb = vbits_all + m * kN;
    const int lane = threadIdx.x;

    __shared__ float u[kN], v[kN];
    __shared__ int xr[kN], yc[kN];     // row->col, col->row
    __shared__ int2 sp[kN];            // (bits of shortest dist, pred row)
    __shared__ int steps[kN];          // popped columns, in pop order
    __shared__ int2 yu[kN];            // (yc[j], bits of u[yc[j]])
    __shared__ int2 rbatch[kN];        // (row, u_bits) to relax this iteration
    __shared__ int flA[kN], flB[kN];   // ping-pong free-row lists
    __shared__ int fcl[kN];            // free-column list
    __shared__ int nf_sh, fc_sh;

    // --- init: v from column minima; clear assignment ---
    for (int j = lane; j < kN; j += 64) {
        v[j] = __uint_as_float(vb[j]);
        xr[j] = -1; yc[j] = -1;
        yu[j] = make_int2(-1, 0);
    }
    __syncthreads();

    float vreg[6];
    #pragma unroll
    for (int r = 0; r < 6; ++r) vreg[r] = v[lane + 64 * r];

    // --- fused u-init + greedy tight assignment (row-major, coalesced) ---
    unsigned freemask = 0x3F;          // this lane's 6 columns free?
    int nf = 0;
    for (int i = 0; i < kN; ++i) {
        const float* Crow = C + (size_t)i * kN;
        float m1 = kInf; int j1loc = 0;
        #pragma unroll
        for (int r = 0; r < 6; ++r) {
            int j = lane + 64 * r;
            float hh = Crow[j] - vreg[r];
            if (hh < m1) { m1 = hh; j1loc = j; }
        }
        float w1 = wave_min_bcast(m1);
        int cloc = (m1 == w1 && ((freemask >> (j1loc >> 6)) & 1u)) ? j1loc : (1 << 30);
        unsigned long long mk = __ballot(cloc < (1 << 30));
        if (mk) {
            int cand = __builtin_amdgcn_readlane(cloc, __ffsll(mk) - 1);
            if (lane == (cand & 63)) freemask &= ~(1u << (cand >> 6));
            if (lane == 0) {
                xr[i] = cand; yc[cand] = i; u[i] = w1;
                yu[cand] = make_int2(i, __float_as_int(w1));
            }
        } else {
            if (lane == 0) { flA[nf] = i; u[i] = w1; }
            ++nf;
        }
    }

    // --- augmenting row reduction, 2 passes, tight-only, ping-pong lists ---
    // Displaced rows get xr=-1 (multi-source SAP relies on the invariant).
    int* src = flA; int* dst = flB;
    int f0 = nf;
    for (int pass = 0; pass < 2 && f0 > 0; ++pass) {
        int k = 0, f = 0, ops = 0;
        int i = -1;
        bool capped = false;
        for (;;) {
            if (i < 0) {
                if (k >= f0) break;
                i = src[k]; ++k;                     // uniform LDS broadcast
            }
            if (++ops > 4 * kN) {                    // churn guard
                if (lane == 0) { dst[f] = i; xr[i] = -1; }
                ++f; capped = true; break;
            }
            const float* Crow = C + (size_t)i * kN;
            float m1 = kInf, m2 = kInf; int j1loc = 0;
            #pragma unroll
            for (int r = 0; r < 6; ++r) {
                int j = lane + 64 * r;
                float hh = Crow[j] - vreg[r];
                if (hh < m1) { m2 = m1; m1 = hh; j1loc = j; }
                else if (hh < m2) { m2 = hh; }
            }
            float w1, w2;
            wave_min2_bcast(m1, m2, w1, w2);
            unsigned long long mk = __ballot(m1 == w1);
            int j1 = __builtin_amdgcn_readlane(j1loc, __ffsll(mk) - 1);
            bool strict = (w1 < w2);
            int i0 = yc[j1];                         // uniform
            if (strict) {
                if (lane == (j1 & 63)) {
                    float nv = vreg[j1 >> 6] - (w2 - w1);
                    vreg[j1 >> 6] = nv; v[j1] = nv;
                }
                float uin = Crow[j1] - v[j1];        // uniform load + LDS read
                if (lane == 0) {
                    xr[i] = j1; yc[j1] = i; u[i] = uin;
                    yu[j1] = make_int2(i, __float_as_int(uin));
                    if (i0 >= 0) xr[i0] = -1;        // displaced: now free
                }
                i = (i0 >= 0) ? i0 : -1;
            } else {
                if (lane == 0) {
                    xr[i] = j1; yc[j1] = i; u[i] = w1;
                    yu[j1] = make_int2(i, __float_as_int(w1));
                    if (i0 >= 0) { dst[f] = i0; xr[i0] = -1; }
                }
                if (i0 >= 0) ++f;
                i = -1;
            }
        }
        if (capped) {                                // append unprocessed tail
            for (int t = k + lane; t < f0; t += 64) dst[f + (t - k)] = src[t];
            f += f0 - k;
        }
        int* tmp = src; src = dst; dst = tmp;
        f0 = f;
    }
    __syncthreads();

    // --- build free-column list ---
    {
        int fc = 0;
        for (int base = 0; base < kN; base += 64) {
            int j = base + lane;
            bool isfree = (yc[j] < 0);
            unsigned long long mk = __ballot(isfree);
            int pos = fc + __popcll(mk & ((1ull << lane) - 1ull));
            if (isfree) fcl[pos] = j;
            fc += (int)__popcll(mk);
        }
        if (lane == 0) { fc_sh = fc; nf_sh = f0; }
    }
    __syncthreads();

    // --- MULTI-SOURCE SAP phases with per-phase free-column dual refresh ---
    while (true) {
        const int nfr = nf_sh;
        if (nfr <= 0) break;

        // refresh v[j] = min_i (C_ij - u_i) for every remaining free column.
        // Only raises free-column v to exact tightness -> feasible, exact.
        {
            const int fc = fc_sh;
            for (int t = lane; t < fc; t += 64) {
                int j = fcl[t];
                float mn = kInf;
                if (have_ct) {
                    const float4* Rt = (const float4*)(CT + (size_t)j * kN);
                    #pragma unroll 4
                    for (int q = 0; q < kN / 4; ++q) {
                        float4 cv = Rt[q];
                        mn = fminf(mn, cv.x - u[4 * q + 0]);
                        mn = fminf(mn, cv.y - u[4 * q + 1]);
                        mn = fminf(mn, cv.z - u[4 * q + 2]);
                        mn = fminf(mn, cv.w - u[4 * q + 3]);
                    }
                } else {
                    #pragma unroll 4
                    for (int i = 0; i < kN; ++i)
                        mn = fminf(mn, C[(size_t)i * kN + j] - u[i]);
                }
                v[j] = mn;
            }
        }
        __syncthreads();

        float sreg[6];
        unsigned scmask = 0;
        #pragma unroll
        for (int r = 0; r < 6; ++r) { sreg[r] = kInf; vreg[r] = v[lane + 64 * r]; }
        float min_val = 0.0f;
        int sink = -1, scount = 0, iters = 0;
        int nbatch = nfr;
        for (int t = lane; t < nfr; t += 64) {
            int rr = src[t];
            rbatch[t] = make_int2(rr, __float_as_int(u[rr]));
        }
        __syncthreads();

        while (true) {
            // relax rows in rbatch. d = min_val + ((c - v) - u): tight edges
            // reproduce ~min_val (ulp) -> free cols pop almost immediately.
            if (nbatch == 1) {                       // fast path: no dup loads
                int2 e = rbatch[0];
                float uu = __int_as_float(e.y);
                const float* R = C + (size_t)e.x * kN;
                float cc[6];
                #pragma unroll
                for (int r = 0; r < 6; ++r) cc[r] = R[lane + 64 * r];
                #pragma unroll
                for (int r = 0; r < 6; ++r) {
                    float d = min_val + ((cc[r] - vreg[r]) - uu);
                    bool notsc = ((scmask >> r) & 1u) == 0u;
                    if (notsc && d < sreg[r]) {
                        sreg[r] = d;
                        sp[lane + 64 * r] = make_int2(__float_as_int(d), e.x);
                    }
                }
            } else {
                for (int t0 = 0; t0 < nbatch; t0 += 4) {
                    int rw[4]; const float* R[4]; float uu[4];
                    #pragma unroll
                    for (int q = 0; q < 4; ++q) {
                        int idx = t0 + q; if (idx >= nbatch) idx = nbatch - 1;
                        int2 e = rbatch[idx];
                        rw[q] = e.x;
                        uu[q] = __int_as_float(e.y);
                        R[q]  = C + (size_t)e.x * kN;
                    }
                    float cc[4][6];
                    #pragma unroll
                    for (int q = 0; q < 4; ++q) {
                        #pragma unroll
                        for (int r = 0; r < 6; ++r) cc[q][r] = R[q][lane + 64 * r];
                    }
                    #pragma unroll
                    for (int r = 0; r < 6; ++r) {
                        float db = sreg[r]; int pred = -1;
                        #pragma unroll
                        for (int q = 0; q < 4; ++q) {
                            float d = min_val + ((cc[q][r] - vreg[r]) - uu[q]);
                            if (d < db) { db = d; pred = rw[q]; }
                        }
                        bool notsc = ((scmask >> r) & 1u) == 0u;
                        if (notsc && pred >= 0) {
                            sreg[r] = db;
                            sp[lane + 64 * r] = make_int2(__float_as_int(db), pred);
                        }
                    }
                }
            }

            // global min over remaining (non-popped) columns
            float best = fminf(fminf(fminf(sreg[0], sreg[1]), fminf(sreg[2], sreg[3])),
                               fminf(sreg[4], sreg[5]));
            min_val = wave_min_bcast(best);

            // pop ALL columns at min_val
            nbatch = 0;
            #pragma unroll
            for (int r = 0; r < 6; ++r) {
                bool notsc = ((scmask >> r) & 1u) == 0u;
                bool elig = notsc && (sreg[r] == min_val);
                unsigned long long mk = __ballot(elig);
                if (mk == 0) continue;
                int j = lane + 64 * r;
                int2 p = make_int2(0, 0);
                if (elig) { p = yu[j]; sreg[r] = kInf; scmask |= 1u << r; }
                int pos = (int)__popcll(mk & ((1ull << lane) - 1ull));
                if (elig) {
                    steps[scount + pos] = j;
                    rbatch[nbatch + pos] = p;
                }
                int cnt = (int)__popcll(mk);
                unsigned long long fmk = __ballot(elig && p.x < 0);
                if (fmk != 0 && sink < 0) sink = (__ffsll(fmk) - 1) + 64 * r;
                scount += cnt; nbatch += cnt;
            }
            if (sink >= 0) break;
            if (++iters > kN + 2) break;             // safety; never in practice
            __syncthreads();   // order LDS rbatch writes before next relax
        }

        __syncthreads();
        if (sink < 0) break;                         // safety: bail out

        // v updates per popped column (sink popped at d==delta: no-op there)
        for (int t = lane; t < scount; t += 64) {
            int jc = steps[t];
            v[jc] -= min_val - __int_as_float(sp[jc].x);
        }
        __syncthreads();
        if (lane == 0) {                             // augment; ends at a free row
            int j = sink;
            int matched = -1;
            int guard = 0;
            for (;;) {
                int ii = sp[j].y;
                yc[j] = ii;
                int nxt = xr[ii];
                xr[ii] = j;
                j = nxt;
                if (nxt < 0) { matched = ii; break; }
                if (++guard > kN) { matched = ii; break; }  // safety
            }
            int n2 = nf_sh;                          // remove matched row;
            for (int t = 0; t < n2; ++t) {           // ALWAYS shrink (progress)
                if (src[t] == matched) { src[t] = src[n2 - 1]; break; }
            }
            nf_sh = n2 - 1;
        }
        __syncthreads();
        // recompute u bitwise-tight for every popped column's (new) owner
        for (int t = lane; t < scount; t += 64) {
            int jc = steps[t];
            int yy = yc[jc];
            if (yy >= 0) {
                float un = C[(size_t)yy * kN + jc] - v[jc];
                u[yy] = un;
                yu[jc] = make_int2(yy, __float_as_int(un));
            }
        }
        // remove the (now matched) sink column from the free-column list
        {
            int fcn = fc_sh;
            int hit = -1;
            for (int t = lane; t < fcn; t += 64) if (fcl[t] == sink) hit = t;
            unsigned long long mk = __ballot(hit >= 0);
            if (mk) {
                if (hit >= 0) fcl[hit] = fcl[fcn - 1];
                if (lane == __ffsll(mk) - 1) fc_sh = fcn - 1;
            }
        }
        __syncthreads();
        // remaining free rows: u += delta (standard multi-source dual update)
        for (int t = lane; t < nf_sh; t += 64) u[src[t]] += min_val;
        __syncthreads();
    }

    // --- loss = Sum D + Sum I + Sum_i C[i, x[i]] ---
    float s = 0.0f;
    for (int t = lane; t < kN; t += 64) {
        int c_ = xr[t];
        if (c_ >= 0) s += C[(size_t)t * kN + c_];
        s += Dall[m * kN + t] + Iall[m * kN + t];
    }
    #pragma unroll
    for (int off = 32; off > 0; off >>= 1) s += __shfl_down(s, off);
    if (lane == 0) loss_out[m] = s;
}

// ---- finalize -------------------------------------------------------------

__global__ void finalize(const float* __restrict__ loss_sums,
                         const float* __restrict__ score_w,
                         const float* __restrict__ score_b,
                         const float* __restrict__ avg_v,
                         float* __restrict__ out) {
    float mc[3];
    for (int m = 0; m < 3; ++m) mc[m] = 2.0f * (loss_sums[m] / (float)kNN) / (float)kNN;
    float logits = score_b[0];
    for (int m = 0; m < 3; ++m) logits += score_w[m] * mc[m];
    float score = 1.0f / (1.0f + expf(-logits));
    out[0] = score;
    out[1] = -logf(score) * avg_v[0];
    out[2] = mc[0];
    out[3] = mc[1];
    out[4] = mc[2];
}

// ---------------------------------------------------------------------------

extern "C" void kernel_launch(void* const* d_in, const int* in_sizes, int n_in,
                              void* d_out, int out_size, void* d_ws, size_t ws_size,
                              hipStream_t stream) {
    const int*   ei1 = (const int*)d_in[0];
    const int*   ei2 = (const int*)d_in[1];
    const float* x1  = (const float*)d_in[2];
    const float* x2  = (const float*)d_in[3];
    const float* avg = (const float*)d_in[6];

    const float *w[3], *b[3], *dl[3], *insp[3], *score_w, *score_b;
    if (in_sizes[11] == 8192) {  // dict order
        w[0]=(const float*)d_in[7];  b[0]=(const float*)d_in[8];
        dl[0]=(const float*)d_in[9]; insp[0]=(const float*)d_in[10];
        w[1]=(const float*)d_in[11]; b[1]=(const float*)d_in[12];
        dl[1]=(const float*)d_in[13]; insp[1]=(const float*)d_in[14];
        w[2]=(const float*)d_in[15]; b[2]=(const float*)d_in[16];
        dl[2]=(const float*)d_in[17]; insp[2]=(const float*)d_in[18];
        score_w=(const float*)d_in[19]; score_b=(const float*)d_in[20];
    } else {                     // signature order
        w[0]=(const float*)d_in[7];  b[0]=(const float*)d_in[8];
        w[1]=(const float*)d_in[9];  b[1]=(const float*)d_in[10];
        w[2]=(const float*)d_in[11]; b[2]=(const float*)d_in[12];
        dl[0]=(const float*)d_in[13]; dl[1]=(const float*)d_in[14]; dl[2]=(const float*)d_in[15];
        insp[0]=(const float*)d_in[16]; insp[1]=(const float*)d_in[17]; insp[2]=(const float*)d_in[18];
        score_w=(const float*)d_in[19]; score_b=(const float*)d_in[20];
    }

    // Workspace layout (float offsets)
    float* ws = (float*)d_ws;
    float* f1[3]  = { ws + 0,      ws + 49152,  ws + 73728  };  // 384x{128,64,32}
    float* f2[3]  = { ws + 86016,  ws + 135168, ws + 159744 };
    float* h      = ws + 172032;                                // 384x128 temp
    float* dinv1  = ws + 221184;
    float* dinv2  = ws + 221568;
    float* Dm     = ws + 221952;                                // 3 x 384
    float* Im     = ws + 223104;                                // 3 x 384
    unsigned* vbits = (unsigned*)(ws + 224256);                 // 3 x 384
    float* C      = ws + 225408;                                // 3 x 384 x 384
    float* loss   = ws + 667776;                                // 3
    float* CT     = ws + 667792;                                // 3 x 384 x 384 (optional)
    const size_t need_ct = (667792 + 3 * (size_t)kN * kN) * sizeof(float);
    const int have_ct = (ws_size >= need_ct) ? 1 : 0;

    init_deg<<<6, 64, 0, stream>>>(dinv1, dinv2);
    scatter_deg<<<24, 256, 0, stream>>>(ei1, ei2, dinv1, dinv2);
    deg_to_dinv<<<6, 64, 0, stream>>>(dinv1, dinv2);

    const int Fs[3] = {128, 64, 32};
    for (int g = 0; g < 2; ++g) {
        const float* xin  = g ? x2  : x1;
        const int*   ei   = g ? ei2 : ei1;
        float*       dinv = g ? dinv2 : dinv1;
        float* const* f   = g ? f2 : f1;
        int fin = 32, relu = 0;
        for (int li = 0; li < 3; ++li) {
            int OF = Fs[li];
            int nthr = kN * OF;
            gemm_act<<<(nthr + 255) / 256, 256, 0, stream>>>(xin, w[li], h, fin, OF, relu);
            agg_init<<<(nthr + 255) / 256, 256, 0, stream>>>(h, dinv, b[li], f[li], OF);
            agg_edges<<<(kE * OF + 255) / 256, 256, 0, stream>>>(ei, h, dinv, f[li], OF);
            xin = f[li]; fin = OF; relu = 1;
        }
    }

    hipMemsetAsync(vbits, 0, 3 * kN * sizeof(unsigned), stream);  // 0 == bits of +0.0f

    for (int m = 0; m < 3; ++m) {
        node_dots<<<3, 128, 0, stream>>>(f1[m], dl[m],   Dm + m * kN, Fs[m]);
        node_dots<<<3, 128, 0, stream>>>(f2[m], insp[m], Im + m * kN, Fs[m]);
        build_cost_red<<<dim3(3, kN), 128, 0, stream>>>(f1[m], f2[m], Dm + m * kN,
                                                        Im + m * kN,
                                                        C + (size_t)m * kN * kN,
                                                        CT + (size_t)m * kN * kN, have_ct,
                                                        vbits + m * kN, Fs[m]);
    }

    lap384<<<3, 64, 0, stream>>>(C, CT, have_ct, vbits, Dm, Im, loss);
    finalize<<<1, 1, 0, stream>>>(loss, score_w, score_b, avg, (float*)d_out);
}

// Round 12
// 3546.729 us; speedup vs baseline: 12.8940x; 12.8940x over previous
//
#include <hip/hip_runtime.h>
#include <math.h>

// ---------------------------------------------------------------------------
// GOTSim: GCN features -> reduced 384x384 LAP.
// R12 = R7 structure (single-source JV + batched clip-zero tie-popping,
// proven 32.9ms) + SINKHORN dual warm start (annealed soft-min row/col
// updates, massively parallel, exactness-safe: lap recomputes u bitwise)
// + per-pop micro-opts (nbatch==1 relax fast path, single-ballot pop).
// LAP_768(block) = Sum(D)+Sum(I) + LAP_384(min(0, M_ij - D_i - I_j)).
// ---------------------------------------------------------------------------

namespace {
constexpr int kN   = 384;
constexpr int kNN  = 768;
constexpr int kE   = 3072;
constexpr float kInf = 1e30f;
}

// ---- wave64 reductions via DPP (row_shr 1,2,4,8 + row_bcast 15,31) --------
__device__ __forceinline__ float wave_min_bcast(float xv) {
    float v = xv;
    #define MSTAGE(ctrl) { int t = __builtin_amdgcn_update_dpp(__float_as_int(v), __float_as_int(v), ctrl, 0xF, 0xF, false); v = fminf(v, __int_as_float(t)); }
    MSTAGE(0x111); MSTAGE(0x112); MSTAGE(0x114); MSTAGE(0x118); MSTAGE(0x142); MSTAGE(0x143);
    #undef MSTAGE
    return __int_as_float(__builtin_amdgcn_readlane(__float_as_int(v), 63));
}

__device__ __forceinline__ float wave_sum_bcast(float x) {
    #define SSTAGE(ctrl) { int t = __builtin_amdgcn_update_dpp(0, __float_as_int(x), ctrl, 0xF, 0xF, false); x += __int_as_float(t); }
    SSTAGE(0x111); SSTAGE(0x112); SSTAGE(0x114); SSTAGE(0x118); SSTAGE(0x142); SSTAGE(0x143);
    #undef SSTAGE
    return __int_as_float(__builtin_amdgcn_readlane(__float_as_int(x), 63));
}

// (min, second-min): disabled lanes contribute identity (+inf) via old=INF.
__device__ __forceinline__ void wave_min2_bcast(float m1, float m2, float& w1, float& w2) {
    const int INFB = __float_as_int(kInf);
    #define M2STAGE(ctrl) { \
        int t1 = __builtin_amdgcn_update_dpp(INFB, __float_as_int(m1), ctrl, 0xF, 0xF, false); \
        int t2 = __builtin_amdgcn_update_dpp(INFB, __float_as_int(m2), ctrl, 0xF, 0xF, false); \
        float o1 = __int_as_float(t1); float o2 = __int_as_float(t2); \
        float n2 = fminf(fmaxf(m1, o1), fminf(m2, o2)); \
        m1 = fminf(m1, o1); m2 = n2; }
    M2STAGE(0x111); M2STAGE(0x112); M2STAGE(0x114); M2STAGE(0x118); M2STAGE(0x142); M2STAGE(0x143);
    #undef M2STAGE
    w1 = __int_as_float(__builtin_amdgcn_readlane(__float_as_int(m1), 63));
    w2 = __int_as_float(__builtin_amdgcn_readlane(__float_as_int(m2), 63));
}

// ---- degree / dinv --------------------------------------------------------

__global__ void init_deg(float* deg1, float* deg2) {
    int v = blockIdx.x * blockDim.x + threadIdx.x;
    if (v < kN) { deg1[v] = 1.0f; deg2[v] = 1.0f; }
}

__global__ void scatter_deg(const int* ei1, const int* ei2, float* deg1, float* deg2) {
    int e = blockIdx.x * blockDim.x + threadIdx.x;
    if (e < kE) {
        atomicAdd(&deg1[ei1[kE + e]], 1.0f);
    } else if (e < 2 * kE) {
        atomicAdd(&deg2[ei2[kE + (e - kE)]], 1.0f);
    }
}

__global__ void deg_to_dinv(float* deg1, float* deg2) {
    int v = blockIdx.x * blockDim.x + threadIdx.x;
    if (v < kN) { deg1[v] = rsqrtf(deg1[v]); deg2[v] = rsqrtf(deg2[v]); }
}

// ---- GCN layer ------------------------------------------------------------

__global__ void gemm_act(const float* __restrict__ x, const float* __restrict__ w,
                         float* __restrict__ h, int FIN, int FOUT, int relu) {
    int idx = blockIdx.x * blockDim.x + threadIdx.x;
    if (idx >= kN * FOUT) return;
    int row = idx / FOUT;
    int oc  = idx - row * FOUT;
    float acc = 0.0f;
    for (int k = 0; k < FIN; ++k) {
        float xv = x[row * FIN + k];
        if (relu) xv = fmaxf(xv, 0.0f);
        acc += xv * w[k * FOUT + oc];
    }
    h[idx] = acc;
}

__global__ void agg_init(const float* __restrict__ h, const float* __restrict__ dinv,
                         const float* __restrict__ b, float* __restrict__ out, int F) {
    int idx = blockIdx.x * blockDim.x + threadIdx.x;
    if (idx >= kN * F) return;
    int v = idx / F;
    int f = idx - v * F;
    float dv = dinv[v];
    out[idx] = b[f] + dv * dv * h[idx];
}

__global__ void agg_edges(const int* __restrict__ ei, const float* __restrict__ h,
                          const float* __restrict__ dinv, float* __restrict__ out, int F) {
    int idx = blockIdx.x * blockDim.x + threadIdx.x;
    if (idx >= kE * F) return;
    int e = idx / F;
    int f = idx - e * F;
    int s = ei[e];
    int d = ei[kE + e];
    atomicAdd(&out[d * F + f], dinv[s] * dinv[d] * h[s * F + f]);
}

// ---- diag terms -----------------------------------------------------------

__global__ void node_dots(const float* __restrict__ f, const float* __restrict__ p,
                          float* __restrict__ out, int F) {
    int i = blockIdx.x * blockDim.x + threadIdx.x;
    if (i >= kN) return;
    float acc = 0.0f;
    for (int k = 0; k < F; ++k) acc += f[i * F + k] * p[k];
    out[i] = -acc;
}

// ---- reduced cost matrix (+ optional transpose) + column minima -----------

__global__ void build_cost_red(const float* __restrict__ f1, const float* __restrict__ f2,
                               const float* __restrict__ D, const float* __restrict__ I,
                               float* __restrict__ C, float* __restrict__ CT, int have_ct,
                               unsigned* __restrict__ vbits, int F) {
    int j = blockIdx.x * blockDim.x + threadIdx.x;
    int i = blockIdx.y;
    if (j >= kN) return;
    float acc = 0.0f;
    for (int k = 0; k < F; ++k) acc += f1[i * F + k] * f2[j * F + k];
    float val = (-acc) - D[i] - I[j];
    float c = fminf(0.0f, val);
    C[i * kN + j] = c;
    if (have_ct) CT[(size_t)j * kN + i] = c;
    atomicMax(&vbits[j], __float_as_uint(c));
}

// ---- Sinkhorn dual preprocessor ------------------------------------------
// vb2v_scale: v_sk = colmin (float), s[m] = mean |colmin| (tau scale)
__global__ __launch_bounds__(64) void vb2v_scale(const unsigned* __restrict__ vbits,
                                                 float* __restrict__ v_sk,
                                                 float* __restrict__ s) {
    int m = blockIdx.x, lane = threadIdx.x;
    float a = 0.0f;
    for (int r = 0; r < 6; ++r) {
        int j = lane + 64 * r;
        float vv = __uint_as_float(vbits[m * kN + j]);
        v_sk[m * kN + j] = vv;
        a += fabsf(vv);
    }
    float tot = wave_sum_bcast(a);
    if (lane == 0) s[m] = fmaxf(tot / (float)kN, 1e-6f);
}

// u_i = softmin_j (C_ij - v_j) at temperature tau*s[m]  (coalesced row read)
__global__ __launch_bounds__(64) void sk_row(const float* __restrict__ Call,
                                             const float* __restrict__ v_sk,
                                             float* __restrict__ u_sk,
                                             float tau, const float* __restrict__ s) {
    int i = blockIdx.x, m = blockIdx.y, lane = threadIdx.x;
    float t = tau * s[m];
    const float* R = Call + (size_t)m * kN * kN + (size_t)i * kN;
    float hh[6];
    float mn = kInf;
    #pragma unroll
    for (int r = 0; r < 6; ++r) {
        int j = lane + 64 * r;
        hh[r] = R[j] - v_sk[m * kN + j];
        mn = fminf(mn, hh[r]);
    }
    float wmn = wave_min_bcast(mn);
    float sm = 0.0f;
    #pragma unroll
    for (int r = 0; r < 6; ++r) sm += __expf((wmn - hh[r]) / t);
    float S = wave_sum_bcast(sm);
    if (lane == 0) u_sk[m * kN + i] = wmn - t * __logf(S);
}

// v_j = softmin_i (C_ij - u_i)  (CT coalesced when available, else strided)
__global__ __launch_bounds__(64) void sk_col(const float* __restrict__ Call,
                                             const float* __restrict__ CTall, int have_ct,
                                             const float* __restrict__ u_sk,
                                             float* __restrict__ v_sk,
                                             float tau, const float* __restrict__ s) {
    int j = blockIdx.x, m = blockIdx.y, lane = threadIdx.x;
    float t = tau * s[m];
    float hh[6];
    float mn = kInf;
    if (have_ct) {
        const float* R = CTall + (size_t)m * kN * kN + (size_t)j * kN;
        #pragma unroll
        for (int r = 0; r < 6; ++r) {
            int i = lane + 64 * r;
            hh[r] = R[i] - u_sk[m * kN + i];
            mn = fminf(mn, hh[r]);
        }
    } else {
        const float* Cm = Call + (size_t)m * kN * kN;
        #pragma unroll
        for (int r = 0; r < 6; ++r) {
            int i = lane + 64 * r;
            hh[r] = Cm[(size_t)i * kN + j] - u_sk[m * kN + i];
            mn = fminf(mn, hh[r]);
        }
    }
    float wmn = wave_min_bcast(mn);
    float sm = 0.0f;
    #pragma unroll
    for (int r = 0; r < 6; ++r) sm += __expf((wmn - hh[r]) / t);
    float S = wave_sum_bcast(sm);
    if (lane == 0) v_sk[m * kN + j] = wmn - t * __logf(S);
}

// ---- 384x384 exact JV LAP, one wave per matrix (R7 structure) -------------

__global__ __launch_bounds__(64) void lap384(const float* __restrict__ Call,
                                             const float* __restrict__ v_init,
                                             const float* __restrict__ Dall,
                                             const float* __restrict__ Iall,
                                             float* __restrict__ loss_out) {
    const int m = blockIdx.x;
    const float* C = Call + (size_t)m * kN * kN;
    const int lane = threadIdx.x;

    __shared__ float u[kN], v[kN];
    __shared__ int xr[kN], yc[kN];
    __shared__ int2 sp[kN];            // (bits of shortest dist, pred row)
    __shared__ int2 steps[kN];         // (pre-augment matched row of col, col)
    __shared__ int2 yu[kN];            // (yc[j], bits of u[yc[j]])
    __shared__ int2 rbatch[kN];        // (row, u_bits) to relax
    __shared__ int flA[kN], flB[kN];
    __shared__ int fcl[kN];

    // --- init: v from Sinkhorn duals (exactness-safe warm start) ---
    for (int j = lane; j < kN; j += 64) {
        v[j] = v_init[m * kN + j];
        xr[j] = -1; yc[j] = -1;
        yu[j] = make_int2(-1, 0);
    }
    __syncthreads();

    float vreg[6];
    #pragma unroll
    for (int r = 0; r < 6; ++r) vreg[r] = v[lane + 64 * r];

    // --- fused u-init + greedy tight assignment ---
    unsigned freemask = 0x3F;
    int nf = 0;
    for (int i = 0; i < kN; ++i) {
        const float* Crow = C + (size_t)i * kN;
        float m1 = kInf; int j1loc = 0;
        #pragma unroll
        for (int r = 0; r < 6; ++r) {
            int j = lane + 64 * r;
            float hh = Crow[j] - vreg[r];
            if (hh < m1) { m1 = hh; j1loc = j; }
        }
        float w1 = wave_min_bcast(m1);
        int cloc = (m1 == w1 && ((freemask >> (j1loc >> 6)) & 1u)) ? j1loc : (1 << 30);
        unsigned long long mk = __ballot(cloc < (1 << 30));
        if (mk) {
            int cand = __builtin_amdgcn_readlane(cloc, __ffsll(mk) - 1);
            if (lane == (cand & 63)) freemask &= ~(1u << (cand >> 6));
            if (lane == 0) {
                xr[i] = cand; yc[cand] = i; u[i] = w1;
                yu[cand] = make_int2(i, __float_as_int(w1));
            }
        } else {
            if (lane == 0) { flA[nf] = i; u[i] = w1; }
            ++nf;
        }
    }

    // --- augmenting row reduction, 2 passes, tight-only ---
    int* src = flA; int* dst = flB;
    int f0 = nf;
    for (int pass = 0; pass < 2 && f0 > 0; ++pass) {
        int k = 0, f = 0, ops = 0;
        int i = -1;
        bool capped = false;
        for (;;) {
            if (i < 0) {
                if (k >= f0) break;
                i = src[k]; ++k;
            }
            if (++ops > 4 * kN) {
                if (lane == 0) dst[f] = i;
                ++f; capped = true; break;
            }
            const float* Crow = C + (size_t)i * kN;
            float m1 = kInf, m2 = kInf; int j1loc = 0;
            #pragma unroll
            for (int r = 0; r < 6; ++r) {
                int j = lane + 64 * r;
                float hh = Crow[j] - vreg[r];
                if (hh < m1) { m2 = m1; m1 = hh; j1loc = j; }
                else if (hh < m2) { m2 = hh; }
            }
            float w1, w2;
            wave_min2_bcast(m1, m2, w1, w2);
            unsigned long long mk = __ballot(m1 == w1);
            int j1 = __builtin_amdgcn_readlane(j1loc, __ffsll(mk) - 1);
            bool strict = (w1 < w2);
            int i0 = yc[j1];
            if (strict) {
                if (lane == (j1 & 63)) { vreg[j1 >> 6] -= (w2 - w1); v[j1] = vreg[j1 >> 6]; }
                if (lane == 0) {
                    xr[i] = j1; yc[j1] = i; u[i] = w2;
                    yu[j1] = make_int2(i, __float_as_int(w2));
                }
                i = (i0 >= 0) ? i0 : -1;
            } else {
                if (lane == 0) {
                    xr[i] = j1; yc[j1] = i; u[i] = w1;
                    yu[j1] = make_int2(i, __float_as_int(w1));
                }
                if (i0 >= 0) { if (lane == 0) dst[f] = i0; ++f; }
                i = -1;
            }
        }
        if (capped) {
            for (int t = k + lane; t < f0; t += 64) dst[f + (t - k)] = src[t];
            f += f0 - k;
        }
        int* tmp = src; src = dst; dst = tmp;
        f0 = f;
    }
    __syncthreads();

    // --- free-column dual reduction: v[j] = min_i (C[i][j] - u[i]) ---
    {
        int fc = 0;
        for (int base = 0; base < kN; base += 64) {
            int j = base + lane;
            bool isfree = (yc[j] < 0);
            unsigned long long mk = __ballot(isfree);
            int pos = fc + __popcll(mk & ((1ull << lane) - 1ull));
            if (isfree) fcl[pos] = j;
            fc += (int)__popcll(mk);
        }
        __syncthreads();
        for (int t = lane; t < fc; t += 64) {
            int j = fcl[t];
            float mn = kInf;
            #pragma unroll 4
            for (int i = 0; i < kN; ++i)
                mn = fminf(mn, C[(size_t)i * kN + j] - u[i]);
            v[j] = mn;
        }
        __syncthreads();
    }

    // --- shortest augmenting path, batched tie-popping + fast paths --------
    const int nfree = f0;
    for (int fi = 0; fi < nfree; ++fi) {
        const int cur = src[fi];
        float sreg[6];
        unsigned scmask = 0;
        #pragma unroll
        for (int r = 0; r < 6; ++r) { sreg[r] = kInf; vreg[r] = v[lane + 64 * r]; }
        float min_val = 0.0f;
        int sink = -1;
        int scount = 0;
        int nbatch = 1;
        int iters = 0;
        if (lane == 0) rbatch[0] = make_int2(cur, __float_as_int(u[cur]));
        __syncthreads();

        while (true) {
            // ---- relax ----
            if (nbatch == 1) {                       // fast path: 6 loads only
                int2 e = rbatch[0];
                float b0 = min_val - __int_as_float(e.y);
                const float* R = C + (size_t)e.x * kN;
                float cc[6];
                #pragma unroll
                for (int r = 0; r < 6; ++r) cc[r] = R[lane + 64 * r];
                #pragma unroll
                for (int r = 0; r < 6; ++r) {
                    float d = b0 + cc[r] - vreg[r];
                    bool notsc = ((scmask >> r) & 1u) == 0u;
                    if (notsc && d < sreg[r]) {
                        sreg[r] = d;
                        sp[lane + 64 * r] = make_int2(__float_as_int(d), e.x);
                    }
                }
            } else {
                for (int t0 = 0; t0 < nbatch; t0 += 4) {
                    int2 e0 = rbatch[t0];
                    int2 e1 = rbatch[(t0 + 1 < nbatch) ? t0 + 1 : nbatch - 1];
                    int2 e2 = rbatch[(t0 + 2 < nbatch) ? t0 + 2 : nbatch - 1];
                    int2 e3 = rbatch[(t0 + 3 < nbatch) ? t0 + 3 : nbatch - 1];
                    float b0 = min_val - __int_as_float(e0.y);
                    float b1 = min_val - __int_as_float(e1.y);
                    float b2 = min_val - __int_as_float(e2.y);
                    float b3 = min_val - __int_as_float(e3.y);
                    const float* R0 = C + (size_t)e0.x * kN;
                    const float* R1 = C + (size_t)e1.x * kN;
                    const float* R2 = C + (size_t)e2.x * kN;
                    const float* R3 = C + (size_t)e3.x * kN;
                    float c0[6], c1[6], c2[6], c3[6];
                    #pragma unroll
                    for (int r = 0; r < 6; ++r) {
                        int j = lane + 64 * r;
                        c0[r] = R0[j]; c1[r] = R1[j]; c2[r] = R2[j]; c3[r] = R3[j];
                    }
                    #pragma unroll
                    for (int r = 0; r < 6; ++r) {
                        float db = sreg[r]; int pred = -1;
                        float d0 = b0 + c0[r] - vreg[r];
                        if (d0 < db) { db = d0; pred = e0.x; }
                        float d1 = b1 + c1[r] - vreg[r];
                        if (d1 < db) { db = d1; pred = e1.x; }
                        float d2 = b2 + c2[r] - vreg[r];
                        if (d2 < db) { db = d2; pred = e2.x; }
                        float d3 = b3 + c3[r] - vreg[r];
                        if (d3 < db) { db = d3; pred = e3.x; }
                        bool notsc = ((scmask >> r) & 1u) == 0u;
                        if (notsc && pred >= 0) {
                            sreg[r] = db;
                            sp[lane + 64 * r] = make_int2(__float_as_int(db), pred);
                        }
                    }
                }
            }

            // ---- global min ----
            float best = fminf(fminf(fminf(sreg[0], sreg[1]), fminf(sreg[2], sreg[3])),
                               fminf(sreg[4], sreg[5]));
            min_val = wave_min_bcast(best);
            if (!(min_val < kInf)) break;            // safety

            // ---- pop: single-ballot fast path, 6-ballot batch fallback ----
            int myreg = -1, hits = 0;
            #pragma unroll
            for (int r = 0; r < 6; ++r) {
                if (sreg[r] == min_val) { if (myreg < 0) myreg = r; ++hits; }
            }
            unsigned long long hmk = __ballot(myreg >= 0);
            int nl = (int)__popcll(hmk);
            int L = __ffsll(hmk) - 1;
            int hcnt = __builtin_amdgcn_readlane(hits, L);
            if (nl == 1 && hcnt == 1) {
                int hreg = __builtin_amdgcn_readlane(myreg, L);
                int bj = L + 64 * hreg;
                if (lane == L) { sreg[hreg] = kInf; scmask |= 1u << hreg; }
                int2 p = yu[bj];                     // broadcast LDS read
                if (lane == 0) {
                    steps[scount] = make_int2(p.x, bj);
                    rbatch[0] = p;
                }
                ++scount; nbatch = 1;
                if (p.x < 0) sink = bj;
            } else {
                nbatch = 0;
                #pragma unroll
                for (int r = 0; r < 6; ++r) {
                    bool notsc = ((scmask >> r) & 1u) == 0u;
                    bool elig = notsc && (sreg[r] == min_val);
                    unsigned long long mk = __ballot(elig);
                    if (mk == 0) continue;
                    int j = lane + 64 * r;
                    int2 p = make_int2(0, 0);
                    if (elig) { p = yu[j]; sreg[r] = kInf; scmask |= 1u << r; }
                    int pos = (int)__popcll(mk & ((1ull << lane) - 1ull));
                    if (elig) {
                        steps[scount + pos] = make_int2(p.x, j);
                        rbatch[nbatch + pos] = p;
                    }
                    int cnt = (int)__popcll(mk);
                    unsigned long long fmk = __ballot(elig && p.x < 0);
                    if (fmk != 0 && sink < 0) sink = (__ffsll(fmk) - 1) + 64 * r;
                    scount += cnt; nbatch += cnt;
                }
            }
            if (sink >= 0) break;
            if (++iters > kN + 2) break;             // safety
            __syncthreads();
        }

        __syncthreads();
        if (sink >= 0) {
            for (int t = lane; t < scount; t += 64) {
                int2 sij = steps[t];
                int i = sij.x, jc = sij.y;
                float adj = min_val - __int_as_float(sp[jc].x);
                v[jc] -= adj;
                if (i >= 0) u[i] += adj;
            }
            if (lane == 0) u[cur] += min_val;
            __syncthreads();
            if (lane == 0) {
                int j = sink;
                int guard = 0;
                for (;;) {
                    int ii = sp[j].y;
                    yc[j] = ii;
                    int nxt = xr[ii];
                    xr[ii] = j;
                    j = nxt;
                    if (ii == cur) break;
                    if (++guard > kN) break;         // safety
                }
            }
            __syncthreads();
            for (int t = lane; t < scount; t += 64) {
                int jc = steps[t].y;
                int yy = yc[jc];
                yu[jc] = make_int2(yy, (yy >= 0) ? __float_as_int(u[yy]) : 0);
            }
            __syncthreads();
        }
    }

    // --- loss = Sum D + Sum I + Sum_i C[i, x[i]] ---
    float s = 0.0f;
    for (int t = lane; t < kN; t += 64) {
        int c_ = xr[t];
        if (c_ >= 0) s += C[(size_t)t * kN + c_];
        s += Dall[m * kN + t] + Iall[m * kN + t];
    }
    #pragma unroll
    for (int off = 32; off > 0; off >>= 1) s += __shfl_down(s, off);
    if (lane == 0) loss_out[m] = s;
}

// ---- finalize -------------------------------------------------------------

__global__ void finalize(const float* __restrict__ loss_sums,
                         const float* __restrict__ score_w,
                         const float* __restrict__ score_b,
                         const float* __restrict__ avg_v,
                         float* __restrict__ out) {
    float mc[3];
    for (int m = 0; m < 3; ++m) mc[m] = 2.0f * (loss_sums[m] / (float)kNN) / (float)kNN;
    float logits = score_b[0];
    for (int m = 0; m < 3; ++m) logits += score_w[m] * mc[m];
    float score = 1.0f / (1.0f + expf(-logits));
    out[0] = score;
    out[1] = -logf(score) * avg_v[0];
    out[2] = mc[0];
    out[3] = mc[1];
    out[4] = mc[2];
}

// ---------------------------------------------------------------------------

extern "C" void kernel_launch(void* const* d_in, const int* in_sizes, int n_in,
                              void* d_out, int out_size, void* d_ws, size_t ws_size,
                              hipStream_t stream) {
    const int*   ei1 = (const int*)d_in[0];
    const int*   ei2 = (const int*)d_in[1];
    const float* x1  = (const float*)d_in[2];
    const float* x2  = (const float*)d_in[3];
    const float* avg = (const float*)d_in[6];

    const float *w[3], *b[3], *dl[3], *insp[3], *score_w, *score_b;
    if (in_sizes[11] == 8192) {  // dict order
        w[0]=(const float*)d_in[7];  b[0]=(const float*)d_in[8];
        dl[0]=(const float*)d_in[9]; insp[0]=(const float*)d_in[10];
        w[1]=(const float*)d_in[11]; b[1]=(const float*)d_in[12];
        dl[1]=(const float*)d_in[13]; insp[1]=(const float*)d_in[14];
        w[2]=(const float*)d_in[15]; b[2]=(const float*)d_in[16];
        dl[2]=(const float*)d_in[17]; insp[2]=(const float*)d_in[18];
        score_w=(const float*)d_in[19]; score_b=(const float*)d_in[20];
    } else {                     // signature order
        w[0]=(const float*)d_in[7];  b[0]=(const float*)d_in[8];
        w[1]=(const float*)d_in[9];  b[1]=(const float*)d_in[10];
        w[2]=(const float*)d_in[11]; b[2]=(const float*)d_in[12];
        dl[0]=(const float*)d_in[13]; dl[1]=(const float*)d_in[14]; dl[2]=(const float*)d_in[15];
        insp[0]=(const float*)d_in[16]; insp[1]=(const float*)d_in[17]; insp[2]=(const float*)d_in[18];
        score_w=(const float*)d_in[19]; score_b=(const float*)d_in[20];
    }

    // Workspace layout (float offsets)
    float* ws = (float*)d_ws;
    float* f1[3]  = { ws + 0,      ws + 49152,  ws + 73728  };
    float* f2[3]  = { ws + 86016,  ws + 135168, ws + 159744 };
    float* h      = ws + 172032;
    float* dinv1  = ws + 221184;
    float* dinv2  = ws + 221568;
    float* Dm     = ws + 221952;
    float* Im     = ws + 223104;
    unsigned* vbits = (unsigned*)(ws + 224256);                 // 3 x 384
    float* C      = ws + 225408;                                // 3 x 384 x 384
    float* loss   = ws + 667776;                                // 3 (+pad)
    float* u_sk   = ws + 667792;                                // 3 x 384
    float* v_sk   = ws + 668944;                                // 3 x 384
    float* s_sk   = ws + 670096;                                // 3
    float* CT     = ws + 670112;                                // 3 x 384 x 384 (optional)
    const size_t need_ct = (670112 + 3 * (size_t)kN * kN) * sizeof(float);
    const int have_ct = (ws_size >= need_ct) ? 1 : 0;

    init_deg<<<6, 64, 0, stream>>>(dinv1, dinv2);
    scatter_deg<<<24, 256, 0, stream>>>(ei1, ei2, dinv1, dinv2);
    deg_to_dinv<<<6, 64, 0, stream>>>(dinv1, dinv2);

    const int Fs[3] = {128, 64, 32};
    for (int g = 0; g < 2; ++g) {
        const float* xin  = g ? x2  : x1;
        const int*   ei   = g ? ei2 : ei1;
        float*       dinv = g ? dinv2 : dinv1;
        float* const* f   = g ? f2 : f1;
        int fin = 32, relu = 0;
        for (int li = 0; li < 3; ++li) {
            int OF = Fs[li];
            int nthr = kN * OF;
            gemm_act<<<(nthr + 255) / 256, 256, 0, stream>>>(xin, w[li], h, fin, OF, relu);
            agg_init<<<(nthr + 255) / 256, 256, 0, stream>>>(h, dinv, b[li], f[li], OF);
            agg_edges<<<(kE * OF + 255) / 256, 256, 0, stream>>>(ei, h, dinv, f[li], OF);
            xin = f[li]; fin = OF; relu = 1;
        }
    }

    hipMemsetAsync(vbits, 0, 3 * kN * sizeof(unsigned), stream);  // 0 == bits of +0.0f

    for (int m = 0; m < 3; ++m) {
        node_dots<<<3, 128, 0, stream>>>(f1[m], dl[m],   Dm + m * kN, Fs[m]);
        node_dots<<<3, 128, 0, stream>>>(f2[m], insp[m], Im + m * kN, Fs[m]);
        build_cost_red<<<dim3(3, kN), 128, 0, stream>>>(f1[m], f2[m], Dm + m * kN,
                                                        Im + m * kN,
                                                        C + (size_t)m * kN * kN,
                                                        CT + (size_t)m * kN * kN, have_ct,
                                                        vbits + m * kN, Fs[m]);
    }

    // Sinkhorn dual warm start: annealed soft row/col reductions (parallel).
    vb2v_scale<<<3, 64, 0, stream>>>(vbits, v_sk, s_sk);
    float tau = 0.8f;
    for (int t = 0; t < 16; ++t) {
        sk_row<<<dim3(kN, 3), 64, 0, stream>>>(C, v_sk, u_sk, tau, s_sk);
        sk_col<<<dim3(kN, 3), 64, 0, stream>>>(C, CT, have_ct, u_sk, v_sk, tau, s_sk);
        tau *= 0.65f;
    }

    lap384<<<3, 64, 0, stream>>>(C, v_sk, Dm, Im, loss);
    finalize<<<1, 1, 0, stream>>>(loss, score_w, score_b, avg, (float*)d_out);
}

// Round 13
// 2448.596 us; speedup vs baseline: 18.6766x; 1.4485x over previous
//
#include <hip/hip_runtime.h>
#include <math.h>

// ---------------------------------------------------------------------------
// GOTSim: GCN features -> reduced 384x384 LAP.
// R13 = R12 (Sinkhorn dual warm start + JV, 3.55ms) +
//   parallel row-reduce/claim greedy (was wave-serial 384 iters),
//   sharper Sinkhorn anneal (20 iters, x0.7),
//   register-carried single-row relax (no rbatch LDS in fast path),
//   tighter ARR cap.
// LAP_768(block) = Sum(D)+Sum(I) + LAP_384(min(0, M_ij - D_i - I_j)).
// ---------------------------------------------------------------------------

namespace {
constexpr int kN   = 384;
constexpr int kNN  = 768;
constexpr int kE   = 3072;
constexpr float kInf = 1e30f;
}

// ---- wave64 reductions via DPP (row_shr 1,2,4,8 + row_bcast 15,31) --------
__device__ __forceinline__ float wave_min_bcast(float xv) {
    float v = xv;
    #define MSTAGE(ctrl) { int t = __builtin_amdgcn_update_dpp(__float_as_int(v), __float_as_int(v), ctrl, 0xF, 0xF, false); v = fminf(v, __int_as_float(t)); }
    MSTAGE(0x111); MSTAGE(0x112); MSTAGE(0x114); MSTAGE(0x118); MSTAGE(0x142); MSTAGE(0x143);
    #undef MSTAGE
    return __int_as_float(__builtin_amdgcn_readlane(__float_as_int(v), 63));
}

__device__ __forceinline__ float wave_sum_bcast(float x) {
    #define SSTAGE(ctrl) { int t = __builtin_amdgcn_update_dpp(0, __float_as_int(x), ctrl, 0xF, 0xF, false); x += __int_as_float(t); }
    SSTAGE(0x111); SSTAGE(0x112); SSTAGE(0x114); SSTAGE(0x118); SSTAGE(0x142); SSTAGE(0x143);
    #undef SSTAGE
    return __int_as_float(__builtin_amdgcn_readlane(__float_as_int(x), 63));
}

// (min, second-min): disabled lanes contribute identity (+inf) via old=INF.
__device__ __forceinline__ void wave_min2_bcast(float m1, float m2, float& w1, float& w2) {
    const int INFB = __float_as_int(kInf);
    #define M2STAGE(ctrl) { \
        int t1 = __builtin_amdgcn_update_dpp(INFB, __float_as_int(m1), ctrl, 0xF, 0xF, false); \
        int t2 = __builtin_amdgcn_update_dpp(INFB, __float_as_int(m2), ctrl, 0xF, 0xF, false); \
        float o1 = __int_as_float(t1); float o2 = __int_as_float(t2); \
        float n2 = fminf(fmaxf(m1, o1), fminf(m2, o2)); \
        m1 = fminf(m1, o1); m2 = n2; }
    M2STAGE(0x111); M2STAGE(0x112); M2STAGE(0x114); M2STAGE(0x118); M2STAGE(0x142); M2STAGE(0x143);
    #undef M2STAGE
    w1 = __int_as_float(__builtin_amdgcn_readlane(__float_as_int(m1), 63));
    w2 = __int_as_float(__builtin_amdgcn_readlane(__float_as_int(m2), 63));
}

// ---- degree / dinv --------------------------------------------------------

__global__ void init_deg(float* deg1, float* deg2) {
    int v = blockIdx.x * blockDim.x + threadIdx.x;
    if (v < kN) { deg1[v] = 1.0f; deg2[v] = 1.0f; }
}

__global__ void scatter_deg(const int* ei1, const int* ei2, float* deg1, float* deg2) {
    int e = blockIdx.x * blockDim.x + threadIdx.x;
    if (e < kE) {
        atomicAdd(&deg1[ei1[kE + e]], 1.0f);
    } else if (e < 2 * kE) {
        atomicAdd(&deg2[ei2[kE + (e - kE)]], 1.0f);
    }
}

__global__ void deg_to_dinv(float* deg1, float* deg2) {
    int v = blockIdx.x * blockDim.x + threadIdx.x;
    if (v < kN) { deg1[v] = rsqrtf(deg1[v]); deg2[v] = rsqrtf(deg2[v]); }
}

// ---- GCN layer ------------------------------------------------------------

__global__ void gemm_act(const float* __restrict__ x, const float* __restrict__ w,
                         float* __restrict__ h, int FIN, int FOUT, int relu) {
    int idx = blockIdx.x * blockDim.x + threadIdx.x;
    if (idx >= kN * FOUT) return;
    int row = idx / FOUT;
    int oc  = idx - row * FOUT;
    float acc = 0.0f;
    for (int k = 0; k < FIN; ++k) {
        float xv = x[row * FIN + k];
        if (relu) xv = fmaxf(xv, 0.0f);
        acc += xv * w[k * FOUT + oc];
    }
    h[idx] = acc;
}

__global__ void agg_init(const float* __restrict__ h, const float* __restrict__ dinv,
                         const float* __restrict__ b, float* __restrict__ out, int F) {
    int idx = blockIdx.x * blockDim.x + threadIdx.x;
    if (idx >= kN * F) return;
    int v = idx / F;
    int f = idx - v * F;
    float dv = dinv[v];
    out[idx] = b[f] + dv * dv * h[idx];
}

__global__ void agg_edges(const int* __restrict__ ei, const float* __restrict__ h,
                          const float* __restrict__ dinv, float* __restrict__ out, int F) {
    int idx = blockIdx.x * blockDim.x + threadIdx.x;
    if (idx >= kE * F) return;
    int e = idx / F;
    int f = idx - e * F;
    int s = ei[e];
    int d = ei[kE + e];
    atomicAdd(&out[d * F + f], dinv[s] * dinv[d] * h[s * F + f]);
}

// ---- diag terms -----------------------------------------------------------

__global__ void node_dots(const float* __restrict__ f, const float* __restrict__ p,
                          float* __restrict__ out, int F) {
    int i = blockIdx.x * blockDim.x + threadIdx.x;
    if (i >= kN) return;
    float acc = 0.0f;
    for (int k = 0; k < F; ++k) acc += f[i * F + k] * p[k];
    out[i] = -acc;
}

// ---- reduced cost matrix (+ optional transpose) + column minima -----------

__global__ void build_cost_red(const float* __restrict__ f1, const float* __restrict__ f2,
                               const float* __restrict__ D, const float* __restrict__ I,
                               float* __restrict__ C, float* __restrict__ CT, int have_ct,
                               unsigned* __restrict__ vbits, int F) {
    int j = blockIdx.x * blockDim.x + threadIdx.x;
    int i = blockIdx.y;
    if (j >= kN) return;
    float acc = 0.0f;
    for (int k = 0; k < F; ++k) acc += f1[i * F + k] * f2[j * F + k];
    float val = (-acc) - D[i] - I[j];
    float c = fminf(0.0f, val);
    C[i * kN + j] = c;
    if (have_ct) CT[(size_t)j * kN + i] = c;
    atomicMax(&vbits[j], __float_as_uint(c));
}

// ---- Sinkhorn dual preprocessor ------------------------------------------

__global__ __launch_bounds__(64) void vb2v_scale(const unsigned* __restrict__ vbits,
                                                 float* __restrict__ v_sk,
                                                 float* __restrict__ s) {
    int m = blockIdx.x, lane = threadIdx.x;
    float a = 0.0f;
    for (int r = 0; r < 6; ++r) {
        int j = lane + 64 * r;
        float vv = __uint_as_float(vbits[m * kN + j]);
        v_sk[m * kN + j] = vv;
        a += fabsf(vv);
    }
    float tot = wave_sum_bcast(a);
    if (lane == 0) s[m] = fmaxf(tot / (float)kN, 1e-6f);
}

__global__ __launch_bounds__(64) void sk_row(const float* __restrict__ Call,
                                             const float* __restrict__ v_sk,
                                             float* __restrict__ u_sk,
                                             float tau, const float* __restrict__ s) {
    int i = blockIdx.x, m = blockIdx.y, lane = threadIdx.x;
    float t = tau * s[m];
    const float* R = Call + (size_t)m * kN * kN + (size_t)i * kN;
    float hh[6];
    float mn = kInf;
    #pragma unroll
    for (int r = 0; r < 6; ++r) {
        int j = lane + 64 * r;
        hh[r] = R[j] - v_sk[m * kN + j];
        mn = fminf(mn, hh[r]);
    }
    float wmn = wave_min_bcast(mn);
    float sm = 0.0f;
    #pragma unroll
    for (int r = 0; r < 6; ++r) sm += __expf((wmn - hh[r]) / t);
    float S = wave_sum_bcast(sm);
    if (lane == 0) u_sk[m * kN + i] = wmn - t * __logf(S);
}

__global__ __launch_bounds__(64) void sk_col(const float* __restrict__ Call,
                                             const float* __restrict__ CTall, int have_ct,
                                             const float* __restrict__ u_sk,
                                             float* __restrict__ v_sk,
                                             float tau, const float* __restrict__ s) {
    int j = blockIdx.x, m = blockIdx.y, lane = threadIdx.x;
    float t = tau * s[m];
    float hh[6];
    float mn = kInf;
    if (have_ct) {
        const float* R = CTall + (size_t)m * kN * kN + (size_t)j * kN;
        #pragma unroll
        for (int r = 0; r < 6; ++r) {
            int i = lane + 64 * r;
            hh[r] = R[i] - u_sk[m * kN + i];
            mn = fminf(mn, hh[r]);
        }
    } else {
        const float* Cm = Call + (size_t)m * kN * kN;
        #pragma unroll
        for (int r = 0; r < 6; ++r) {
            int i = lane + 64 * r;
            hh[r] = Cm[(size_t)i * kN + j] - u_sk[m * kN + i];
            mn = fminf(mn, hh[r]);
        }
    }
    float wmn = wave_min_bcast(mn);
    float sm = 0.0f;
    #pragma unroll
    for (int r = 0; r < 6; ++r) sm += __expf((wmn - hh[r]) / t);
    float S = wave_sum_bcast(sm);
    if (lane == 0) v_sk[m * kN + j] = wmn - t * __logf(S);
}

// ---- parallel row reduce: u0_i = min_j(C_ij - v_j) + argmin (bitwise) -----
__global__ __launch_bounds__(64) void row_reduce(const float* __restrict__ Call,
                                                 const float* __restrict__ v_sk,
                                                 float* __restrict__ u0,
                                                 int* __restrict__ arg0) {
    int i = blockIdx.x, m = blockIdx.y, lane = threadIdx.x;
    const float* R = Call + (size_t)m * kN * kN + (size_t)i * kN;
    float m1 = kInf; int j1 = 0;
    #pragma unroll
    for (int r = 0; r < 6; ++r) {
        int j = lane + 64 * r;
        float h = R[j] - v_sk[m * kN + j];
        if (h < m1) { m1 = h; j1 = j; }
    }
    float w1 = wave_min_bcast(m1);
    unsigned long long mk = __ballot(m1 == w1);
    int jm = __builtin_amdgcn_readlane(j1, __ffsll(mk) - 1);
    if (lane == 0) { u0[m * kN + i] = w1; arg0[m * kN + i] = jm; }
}

// ---- 384x384 exact JV LAP, one wave per matrix ----------------------------

__global__ __launch_bounds__(64) void lap384(const float* __restrict__ Call,
                                             const float* __restrict__ v_init,
                                             const float* __restrict__ u0,
                                             const int* __restrict__ arg0,
                                             const float* __restrict__ Dall,
                                             const float* __restrict__ Iall,
                                             float* __restrict__ loss_out) {
    const int m = blockIdx.x;
    const float* C = Call + (size_t)m * kN * kN;
    const int lane = threadIdx.x;

    __shared__ float u[kN], v[kN];
    __shared__ int xr[kN], yc[kN];
    __shared__ int2 sp[kN];            // (bits of shortest dist, pred row)
    __shared__ int2 steps[kN];         // (pre-augment matched row of col, col)
    __shared__ int2 yu[kN];            // (yc[j], bits of u[yc[j]])
    __shared__ int2 rbatch[kN];        // (row, u_bits), batch-relax only
    __shared__ int flA[kN], flB[kN];
    __shared__ int fcl[kN];

    // --- init ---
    for (int j = lane; j < kN; j += 64) {
        v[j] = v_init[m * kN + j];
        xr[j] = -1; yc[j] = -1;
        yu[j] = make_int2(-1, 0);
        u[j] = u0[m * kN + j];
    }
    __syncthreads();

    float vreg[6];
    #pragma unroll
    for (int r = 0; r < 6; ++r) vreg[r] = v[lane + 64 * r];

    // --- parallel greedy claim: row i -> arg0[i] via atomicCAS on yc ---
    int nf = 0;
    #pragma unroll
    for (int r = 0; r < 6; ++r) {
        int i = lane + 64 * r;
        int j1 = arg0[m * kN + i];
        int old = atomicCAS(&yc[j1], -1, i);
        bool won = (old == -1);
        if (won) {
            xr[i] = j1;
            yu[j1] = make_int2(i, __float_as_int(u[i]));
        }
        unsigned long long mk = __ballot(!won);
        int pos = nf + (int)__popcll(mk & ((1ull << lane) - 1ull));
        if (!won) flA[pos] = i;
        nf += (int)__popcll(mk);
    }
    __syncthreads();

    // --- augmenting row reduction, 2 passes, tight-only, cap 2*kN ---
    int* src = flA; int* dst = flB;
    int f0 = nf;
    for (int pass = 0; pass < 2 && f0 > 0; ++pass) {
        int k = 0, f = 0, ops = 0;
        int i = -1;
        bool capped = false;
        for (;;) {
            if (i < 0) {
                if (k >= f0) break;
                i = src[k]; ++k;
            }
            if (++ops > 2 * kN) {
                if (lane == 0) dst[f] = i;
                ++f; capped = true; break;
            }
            const float* Crow = C + (size_t)i * kN;
            float m1 = kInf, m2 = kInf; int j1loc = 0;
            #pragma unroll
            for (int r = 0; r < 6; ++r) {
                int j = lane + 64 * r;
                float hh = Crow[j] - vreg[r];
                if (hh < m1) { m2 = m1; m1 = hh; j1loc = j; }
                else if (hh < m2) { m2 = hh; }
            }
            float w1, w2;
            wave_min2_bcast(m1, m2, w1, w2);
            unsigned long long mk = __ballot(m1 == w1);
            int j1 = __builtin_amdgcn_readlane(j1loc, __ffsll(mk) - 1);
            bool strict = (w1 < w2);
            int i0 = yc[j1];
            if (strict) {
                if (lane == (j1 & 63)) { vreg[j1 >> 6] -= (w2 - w1); v[j1] = vreg[j1 >> 6]; }
                if (lane == 0) {
                    xr[i] = j1; yc[j1] = i; u[i] = w2;
                    yu[j1] = make_int2(i, __float_as_int(w2));
                }
                i = (i0 >= 0) ? i0 : -1;
            } else {
                if (lane == 0) {
                    xr[i] = j1; yc[j1] = i; u[i] = w1;
                    yu[j1] = make_int2(i, __float_as_int(w1));
                }
                if (i0 >= 0) { if (lane == 0) dst[f] = i0; ++f; }
                i = -1;
            }
        }
        if (capped) {
            for (int t = k + lane; t < f0; t += 64) dst[f + (t - k)] = src[t];
            f += f0 - k;
        }
        int* tmp = src; src = dst; dst = tmp;
        f0 = f;
    }
    __syncthreads();

    // --- free-column dual reduction: v[j] = min_i (C[i][j] - u[i]) ---
    {
        int fc = 0;
        for (int base = 0; base < kN; base += 64) {
            int j = base + lane;
            bool isfree = (yc[j] < 0);
            unsigned long long mk = __ballot(isfree);
            int pos = fc + __popcll(mk & ((1ull << lane) - 1ull));
            if (isfree) fcl[pos] = j;
            fc += (int)__popcll(mk);
        }
        __syncthreads();
        for (int t = lane; t < fc; t += 64) {
            int j = fcl[t];
            float mn = kInf;
            #pragma unroll 4
            for (int i = 0; i < kN; ++i)
                mn = fminf(mn, C[(size_t)i * kN + j] - u[i]);
            v[j] = mn;
        }
        __syncthreads();
    }

    // --- shortest augmenting path, batched tie-popping, register relax -----
    const int nfree = f0;
    for (int fi = 0; fi < nfree; ++fi) {
        const int cur = src[fi];
        float sreg[6];
        unsigned scmask = 0;
        #pragma unroll
        for (int r = 0; r < 6; ++r) { sreg[r] = kInf; vreg[r] = v[lane + 64 * r]; }
        float min_val = 0.0f;
        int sink = -1;
        int scount = 0;
        int nbatch = 1;
        int iters = 0;
        int er = cur;                              // register-carried row
        int eu = __float_as_int(u[cur]);           // and its u-bits
        __syncthreads();

        while (true) {
            // ---- relax ----
            if (nbatch == 1) {                     // registers, no LDS seed
                float b0 = min_val - __int_as_float(eu);
                const float* R = C + (size_t)er * kN;
                float cc[6];
                #pragma unroll
                for (int r = 0; r < 6; ++r) cc[r] = R[lane + 64 * r];
                #pragma unroll
                for (int r = 0; r < 6; ++r) {
                    float d = b0 + cc[r] - vreg[r];
                    bool notsc = ((scmask >> r) & 1u) == 0u;
                    if (notsc && d < sreg[r]) {
                        sreg[r] = d;
                        sp[lane + 64 * r] = make_int2(__float_as_int(d), er);
                    }
                }
            } else {
                for (int t0 = 0; t0 < nbatch; t0 += 4) {
                    int2 e0 = rbatch[t0];
                    int2 e1 = rbatch[(t0 + 1 < nbatch) ? t0 + 1 : nbatch - 1];
                    int2 e2 = rbatch[(t0 + 2 < nbatch) ? t0 + 2 : nbatch - 1];
                    int2 e3 = rbatch[(t0 + 3 < nbatch) ? t0 + 3 : nbatch - 1];
                    float b0 = min_val - __int_as_float(e0.y);
                    float b1 = min_val - __int_as_float(e1.y);
                    float b2 = min_val - __int_as_float(e2.y);
                    float b3 = min_val - __int_as_float(e3.y);
                    const float* R0 = C + (size_t)e0.x * kN;
                    const float* R1 = C + (size_t)e1.x * kN;
                    const float* R2 = C + (size_t)e2.x * kN;
                    const float* R3 = C + (size_t)e3.x * kN;
                    float c0[6], c1[6], c2[6], c3[6];
                    #pragma unroll
                    for (int r = 0; r < 6; ++r) {
                        int j = lane + 64 * r;
                        c0[r] = R0[j]; c1[r] = R1[j]; c2[r] = R2[j]; c3[r] = R3[j];
                    }
                    #pragma unroll
                    for (int r = 0; r < 6; ++r) {
                        float db = sreg[r]; int pred = -1;
                        float d0 = b0 + c0[r] - vreg[r];
                        if (d0 < db) { db = d0; pred = e0.x; }
                        float d1 = b1 + c1[r] - vreg[r];
                        if (d1 < db) { db = d1; pred = e1.x; }
                        float d2 = b2 + c2[r] - vreg[r];
                        if (d2 < db) { db = d2; pred = e2.x; }
                        float d3 = b3 + c3[r] - vreg[r];
                        if (d3 < db) { db = d3; pred = e3.x; }
                        bool notsc = ((scmask >> r) & 1u) == 0u;
                        if (notsc && pred >= 0) {
                            sreg[r] = db;
                            sp[lane + 64 * r] = make_int2(__float_as_int(db), pred);
                        }
                    }
                }
            }

            // ---- global min ----
            float best = fminf(fminf(fminf(sreg[0], sreg[1]), fminf(sreg[2], sreg[3])),
                               fminf(sreg[4], sreg[5]));
            min_val = wave_min_bcast(best);
            if (!(min_val < kInf)) break;            // safety

            // ---- pop: single-ballot fast path, 6-ballot batch fallback ----
            int myreg = -1, hits = 0;
            #pragma unroll
            for (int r = 0; r < 6; ++r) {
                if (sreg[r] == min_val) { if (myreg < 0) myreg = r; ++hits; }
            }
            unsigned long long hmk = __ballot(myreg >= 0);
            int nl = (int)__popcll(hmk);
            int L = __ffsll(hmk) - 1;
            int hcnt = __builtin_amdgcn_readlane(hits, L);
            if (nl == 1 && hcnt == 1) {
                int hreg = __builtin_amdgcn_readlane(myreg, L);
                int bj = L + 64 * hreg;
                if (lane == L) { sreg[hreg] = kInf; scmask |= 1u << hreg; }
                int2 p = yu[bj];                     // broadcast LDS read
                if (lane == 0) steps[scount] = make_int2(p.x, bj);
                ++scount; nbatch = 1;
                er = p.x; eu = p.y;
                if (p.x < 0) sink = bj;
            } else {
                nbatch = 0;
                #pragma unroll
                for (int r = 0; r < 6; ++r) {
                    bool notsc = ((scmask >> r) & 1u) == 0u;
                    bool elig = notsc && (sreg[r] == min_val);
                    unsigned long long mk = __ballot(elig);
                    if (mk == 0) continue;
                    int j = lane + 64 * r;
                    int2 p = make_int2(0, 0);
                    if (elig) { p = yu[j]; sreg[r] = kInf; scmask |= 1u << r; }
                    int pos = (int)__popcll(mk & ((1ull << lane) - 1ull));
                    if (elig) {
                        steps[scount + pos] = make_int2(p.x, j);
                        rbatch[nbatch + pos] = p;
                    }
                    int cnt = (int)__popcll(mk);
                    unsigned long long fmk = __ballot(elig && p.x < 0);
                    if (fmk != 0 && sink < 0) sink = (__ffsll(fmk) - 1) + 64 * r;
                    scount += cnt; nbatch += cnt;
                }
            }
            if (sink >= 0) break;
            if (++iters > kN + 2) break;             // safety
            __syncthreads();
        }

        __syncthreads();
        if (sink >= 0) {
            for (int t = lane; t < scount; t += 64) {
                int2 sij = steps[t];
                int i = sij.x, jc = sij.y;
                float adj = min_val - __int_as_float(sp[jc].x);
                v[jc] -= adj;
                if (i >= 0) u[i] += adj;
            }
            if (lane == 0) u[cur] += min_val;
            __syncthreads();
            if (lane == 0) {
                int j = sink;
                int guard = 0;
                for (;;) {
                    int ii = sp[j].y;
                    yc[j] = ii;
                    int nxt = xr[ii];
                    xr[ii] = j;
                    j = nxt;
                    if (ii == cur) break;
                    if (++guard > kN) break;         // safety
                }
            }
            __syncthreads();
            for (int t = lane; t < scount; t += 64) {
                int jc = steps[t].y;
                int yy = yc[jc];
                yu[jc] = make_int2(yy, (yy >= 0) ? __float_as_int(u[yy]) : 0);
            }
            __syncthreads();
        }
    }

    // --- loss = Sum D + Sum I + Sum_i C[i, x[i]] ---
    float s = 0.0f;
    for (int t = lane; t < kN; t += 64) {
        int c_ = xr[t];
        if (c_ >= 0) s += C[(size_t)t * kN + c_];
        s += Dall[m * kN + t] + Iall[m * kN + t];
    }
    #pragma unroll
    for (int off = 32; off > 0; off >>= 1) s += __shfl_down(s, off);
    if (lane == 0) loss_out[m] = s;
}

// ---- finalize -------------------------------------------------------------

__global__ void finalize(const float* __restrict__ loss_sums,
                         const float* __restrict__ score_w,
                         const float* __restrict__ score_b,
                         const float* __restrict__ avg_v,
                         float* __restrict__ out) {
    float mc[3];
    for (int m = 0; m < 3; ++m) mc[m] = 2.0f * (loss_sums[m] / (float)kNN) / (float)kNN;
    float logits = score_b[0];
    for (int m = 0; m < 3; ++m) logits += score_w[m] * mc[m];
    float score = 1.0f / (1.0f + expf(-logits));
    out[0] = score;
    out[1] = -logf(score) * avg_v[0];
    out[2] = mc[0];
    out[3] = mc[1];
    out[4] = mc[2];
}

// ---------------------------------------------------------------------------

extern "C" void kernel_launch(void* const* d_in, const int* in_sizes, int n_in,
                              void* d_out, int out_size, void* d_ws, size_t ws_size,
                              hipStream_t stream) {
    const int*   ei1 = (const int*)d_in[0];
    const int*   ei2 = (const int*)d_in[1];
    const float* x1  = (const float*)d_in[2];
    const float* x2  = (const float*)d_in[3];
    const float* avg = (const float*)d_in[6];

    const float *w[3], *b[3], *dl[3], *insp[3], *score_w, *score_b;
    if (in_sizes[11] == 8192) {  // dict order
        w[0]=(const float*)d_in[7];  b[0]=(const float*)d_in[8];
        dl[0]=(const float*)d_in[9]; insp[0]=(const float*)d_in[10];
        w[1]=(const float*)d_in[11]; b[1]=(const float*)d_in[12];
        dl[1]=(const float*)d_in[13]; insp[1]=(const float*)d_in[14];
        w[2]=(const float*)d_in[15]; b[2]=(const float*)d_in[16];
        dl[2]=(const float*)d_in[17]; insp[2]=(const float*)d_in[18];
        score_w=(const float*)d_in[19]; score_b=(const float*)d_in[20];
    } else {                     // signature order
        w[0]=(const float*)d_in[7];  b[0]=(const float*)d_in[8];
        w[1]=(const float*)d_in[9];  b[1]=(const float*)d_in[10];
        w[2]=(const float*)d_in[11]; b[2]=(const float*)d_in[12];
        dl[0]=(const float*)d_in[13]; dl[1]=(const float*)d_in[14]; dl[2]=(const float*)d_in[15];
        insp[0]=(const float*)d_in[16]; insp[1]=(const float*)d_in[17]; insp[2]=(const float*)d_in[18];
        score_w=(const float*)d_in[19]; score_b=(const float*)d_in[20];
    }

    // Workspace layout (float offsets)
    float* ws = (float*)d_ws;
    float* f1[3]  = { ws + 0,      ws + 49152,  ws + 73728  };
    float* f2[3]  = { ws + 86016,  ws + 135168, ws + 159744 };
    float* h      = ws + 172032;
    float* dinv1  = ws + 221184;
    float* dinv2  = ws + 221568;
    float* Dm     = ws + 221952;
    float* Im     = ws + 223104;
    unsigned* vbits = (unsigned*)(ws + 224256);                 // 3 x 384
    float* C      = ws + 225408;                                // 3 x 384 x 384
    float* loss   = ws + 667776;                                // 3 (+pad)
    float* u_sk   = ws + 667792;                                // 3 x 384
    float* v_sk   = ws + 668944;                                // 3 x 384
    float* s_sk   = ws + 670096;                                // 3 (+pad)
    float* u0     = ws + 670112;                                // 3 x 384
    int*   arg0   = (int*)(ws + 671264);                        // 3 x 384
    float* CT     = ws + 672416;                                // 3 x 384 x 384 (optional)
    const size_t need_ct = (672416 + 3 * (size_t)kN * kN) * sizeof(float);
    const int have_ct = (ws_size >= need_ct) ? 1 : 0;

    init_deg<<<6, 64, 0, stream>>>(dinv1, dinv2);
    scatter_deg<<<24, 256, 0, stream>>>(ei1, ei2, dinv1, dinv2);
    deg_to_dinv<<<6, 64, 0, stream>>>(dinv1, dinv2);

    const int Fs[3] = {128, 64, 32};
    for (int g = 0; g < 2; ++g) {
        const float* xin  = g ? x2  : x1;
        const int*   ei   = g ? ei2 : ei1;
        float*       dinv = g ? dinv2 : dinv1;
        float* const* f   = g ? f2 : f1;
        int fin = 32, relu = 0;
        for (int li = 0; li < 3; ++li) {
            int OF = Fs[li];
            int nthr = kN * OF;
            gemm_act<<<(nthr + 255) / 256, 256, 0, stream>>>(xin, w[li], h, fin, OF, relu);
            agg_init<<<(nthr + 255) / 256, 256, 0, stream>>>(h, dinv, b[li], f[li], OF);
            agg_edges<<<(kE * OF + 255) / 256, 256, 0, stream>>>(ei, h, dinv, f[li], OF);
            xin = f[li]; fin = OF; relu = 1;
        }
    }

    hipMemsetAsync(vbits, 0, 3 * kN * sizeof(unsigned), stream);  // 0 == bits of +0.0f

    for (int m = 0; m < 3; ++m) {
        node_dots<<<3, 128, 0, stream>>>(f1[m], dl[m],   Dm + m * kN, Fs[m]);
        node_dots<<<3, 128, 0, stream>>>(f2[m], insp[m], Im + m * kN, Fs[m]);
        build_cost_red<<<dim3(3, kN), 128, 0, stream>>>(f1[m], f2[m], Dm + m * kN,
                                                        Im + m * kN,
                                                        C + (size_t)m * kN * kN,
                                                        CT + (size_t)m * kN * kN, have_ct,
                                                        vbits + m * kN, Fs[m]);
    }

    // Sinkhorn dual warm start: annealed soft row/col reductions (parallel).
    vb2v_scale<<<3, 64, 0, stream>>>(vbits, v_sk, s_sk);
    float tau = 0.8f;
    for (int t = 0; t < 20; ++t) {
        sk_row<<<dim3(kN, 3), 64, 0, stream>>>(C, v_sk, u_sk, tau, s_sk);
        sk_col<<<dim3(kN, 3), 64, 0, stream>>>(C, CT, have_ct, u_sk, v_sk, tau, s_sk);
        tau *= 0.7f;
    }
    // exact parallel row pass: u0 = min_j(C - v), argmin (bitwise-tight)
    row_reduce<<<dim3(kN, 3), 64, 0, stream>>>(C, v_sk, u0, arg0);

    lap384<<<3, 64, 0, stream>>>(C, v_sk, u0, arg0, Dm, Im, loss);
    finalize<<<1, 1, 0, stream>>>(loss, score_w, score_b, avg, (float*)d_out);
}

// Round 14
// 2330.725 us; speedup vs baseline: 19.6212x; 1.0506x over previous
//
#include <hip/hip_runtime.h>
#include <math.h>

// ---------------------------------------------------------------------------
// GOTSim: GCN features -> reduced 384x384 LAP.
// R14 = R13 (Sinkhorn warm start + parallel claim + JV, 2.45ms) +
//   PER-PHASE free-column dual refresh in lap384 (v[j]=min_i(C_ij-u_i) for
//   remaining free cols, CT-coalesced; feasible by construction -> exact),
//   fused GCN kernels (gemm+agg_init, both graphs per launch),
//   batched node_dots/build_cost (struct args), Sinkhorn 16 iters x0.62.
// LAP_768(block) = Sum(D)+Sum(I) + LAP_384(min(0, M_ij - D_i - I_j)).
// ---------------------------------------------------------------------------

namespace {
constexpr int kN   = 384;
constexpr int kNN  = 768;
constexpr int kE   = 3072;
constexpr float kInf = 1e30f;
}

// ---- wave64 reductions via DPP (row_shr 1,2,4,8 + row_bcast 15,31) --------
__device__ __forceinline__ float wave_min_bcast(float xv) {
    float v = xv;
    #define MSTAGE(ctrl) { int t = __builtin_amdgcn_update_dpp(__float_as_int(v), __float_as_int(v), ctrl, 0xF, 0xF, false); v = fminf(v, __int_as_float(t)); }
    MSTAGE(0x111); MSTAGE(0x112); MSTAGE(0x114); MSTAGE(0x118); MSTAGE(0x142); MSTAGE(0x143);
    #undef MSTAGE
    return __int_as_float(__builtin_amdgcn_readlane(__float_as_int(v), 63));
}

__device__ __forceinline__ float wave_sum_bcast(float x) {
    #define SSTAGE(ctrl) { int t = __builtin_amdgcn_update_dpp(0, __float_as_int(x), ctrl, 0xF, 0xF, false); x += __int_as_float(t); }
    SSTAGE(0x111); SSTAGE(0x112); SSTAGE(0x114); SSTAGE(0x118); SSTAGE(0x142); SSTAGE(0x143);
    #undef SSTAGE
    return __int_as_float(__builtin_amdgcn_readlane(__float_as_int(x), 63));
}

// (min, second-min): disabled lanes contribute identity (+inf) via old=INF.
__device__ __forceinline__ void wave_min2_bcast(float m1, float m2, float& w1, float& w2) {
    const int INFB = __float_as_int(kInf);
    #define M2STAGE(ctrl) { \
        int t1 = __builtin_amdgcn_update_dpp(INFB, __float_as_int(m1), ctrl, 0xF, 0xF, false); \
        int t2 = __builtin_amdgcn_update_dpp(INFB, __float_as_int(m2), ctrl, 0xF, 0xF, false); \
        float o1 = __int_as_float(t1); float o2 = __int_as_float(t2); \
        float n2 = fminf(fmaxf(m1, o1), fminf(m2, o2)); \
        m1 = fminf(m1, o1); m2 = n2; }
    M2STAGE(0x111); M2STAGE(0x112); M2STAGE(0x114); M2STAGE(0x118); M2STAGE(0x142); M2STAGE(0x143);
    #undef M2STAGE
    w1 = __int_as_float(__builtin_amdgcn_readlane(__float_as_int(m1), 63));
    w2 = __int_as_float(__builtin_amdgcn_readlane(__float_as_int(m2), 63));
}

// ---- degree / dinv --------------------------------------------------------

__global__ void init_deg(float* deg1, float* deg2) {
    int v = blockIdx.x * blockDim.x + threadIdx.x;
    if (v < kN) { deg1[v] = 1.0f; deg2[v] = 1.0f; }
}

__global__ void scatter_deg(const int* ei1, const int* ei2, float* deg1, float* deg2) {
    int e = blockIdx.x * blockDim.x + threadIdx.x;
    if (e < kE) {
        atomicAdd(&deg1[ei1[kE + e]], 1.0f);
    } else if (e < 2 * kE) {
        atomicAdd(&deg2[ei2[kE + (e - kE)]], 1.0f);
    }
}

__global__ void deg_to_dinv(float* deg1, float* deg2) {
    int v = blockIdx.x * blockDim.x + threadIdx.x;
    if (v < kN) { deg1[v] = rsqrtf(deg1[v]); deg2[v] = rsqrtf(deg2[v]); }
}

// ---- GCN layer: fused gemm+bias+selfloop, both graphs (blockIdx.y) --------

__global__ void gcn_layer(const float* __restrict__ x1in, const float* __restrict__ x2in,
                          const float* __restrict__ w, const float* __restrict__ b,
                          const float* __restrict__ dinv1, const float* __restrict__ dinv2,
                          float* __restrict__ h1, float* __restrict__ h2,
                          float* __restrict__ o1, float* __restrict__ o2,
                          int FIN, int FOUT, int relu) {
    int g = blockIdx.y;
    const float* x    = g ? x2in : x1in;
    const float* dinv = g ? dinv2 : dinv1;
    float* h = g ? h2 : h1;
    float* o = g ? o2 : o1;
    int idx = blockIdx.x * blockDim.x + threadIdx.x;
    if (idx >= kN * FOUT) return;
    int row = idx / FOUT;
    int oc  = idx - row * FOUT;
    float acc = 0.0f;
    for (int k = 0; k < FIN; ++k) {
        float xv = x[row * FIN + k];
        if (relu) xv = fmaxf(xv, 0.0f);
        acc += xv * w[k * FOUT + oc];
    }
    h[idx] = acc;
    float dv = dinv[row];
    o[idx] = b[oc] + dv * dv * acc;
}

__global__ void agg_edges2(const int* __restrict__ ei1, const int* __restrict__ ei2,
                           const float* __restrict__ h1, const float* __restrict__ h2,
                           const float* __restrict__ dinv1, const float* __restrict__ dinv2,
                           float* __restrict__ o1, float* __restrict__ o2, int F) {
    int g = blockIdx.y;
    const int* ei     = g ? ei2 : ei1;
    const float* h    = g ? h2 : h1;
    const float* dinv = g ? dinv2 : dinv1;
    float* out = g ? o2 : o1;
    int idx = blockIdx.x * blockDim.x + threadIdx.x;
    if (idx >= kE * F) return;
    int e = idx / F;
    int f = idx - e * F;
    int s = ei[e];
    int d = ei[kE + e];
    atomicAdd(&out[d * F + f], dinv[s] * dinv[d] * h[s * F + f]);
}

// ---- diag terms: 6 jobs in one launch -------------------------------------

struct DotJob { const float* f; const float* p; float* o; int F; };
struct DotJobs { DotJob j[6]; };

__global__ void node_dots_all(DotJobs jobs) {
    DotJob jb = jobs.j[blockIdx.y];
    int i = blockIdx.x * blockDim.x + threadIdx.x;
    if (i >= kN) return;
    float acc = 0.0f;
    for (int k = 0; k < jb.F; ++k) acc += jb.f[i * jb.F + k] * jb.p[k];
    jb.o[i] = -acc;
}

// ---- reduced cost matrices (all 3) + transpose + column minima ------------

struct CostJob { const float* f1; const float* f2; const float* D; const float* I;
                 float* C; float* CT; unsigned* vb; int F; };
struct CostJobs { CostJob j[3]; };

__global__ void build_cost_all(CostJobs jobs, int have_ct) {
    CostJob jb = jobs.j[blockIdx.z];
    int j = blockIdx.x * blockDim.x + threadIdx.x;
    int i = blockIdx.y;
    if (j >= kN) return;
    float acc = 0.0f;
    for (int k = 0; k < jb.F; ++k) acc += jb.f1[i * jb.F + k] * jb.f2[j * jb.F + k];
    float val = (-acc) - jb.D[i] - jb.I[j];
    float c = fminf(0.0f, val);
    jb.C[i * kN + j] = c;
    if (have_ct) jb.CT[(size_t)j * kN + i] = c;
    atomicMax(&jb.vb[j], __float_as_uint(c));
}

// ---- Sinkhorn dual preprocessor ------------------------------------------

__global__ __launch_bounds__(64) void vb2v_scale(const unsigned* __restrict__ vbits,
                                                 float* __restrict__ v_sk,
                                                 float* __restrict__ s) {
    int m = blockIdx.x, lane = threadIdx.x;
    float a = 0.0f;
    for (int r = 0; r < 6; ++r) {
        int j = lane + 64 * r;
        float vv = __uint_as_float(vbits[m * kN + j]);
        v_sk[m * kN + j] = vv;
        a += fabsf(vv);
    }
    float tot = wave_sum_bcast(a);
    if (lane == 0) s[m] = fmaxf(tot / (float)kN, 1e-6f);
}

__global__ __launch_bounds__(64) void sk_row(const float* __restrict__ Call,
                                             const float* __restrict__ v_sk,
                                             float* __restrict__ u_sk,
                                             float tau, const float* __restrict__ s) {
    int i = blockIdx.x, m = blockIdx.y, lane = threadIdx.x;
    float t = tau * s[m];
    const float* R = Call + (size_t)m * kN * kN + (size_t)i * kN;
    float hh[6];
    float mn = kInf;
    #pragma unroll
    for (int r = 0; r < 6; ++r) {
        int j = lane + 64 * r;
        hh[r] = R[j] - v_sk[m * kN + j];
        mn = fminf(mn, hh[r]);
    }
    float wmn = wave_min_bcast(mn);
    float sm = 0.0f;
    #pragma unroll
    for (int r = 0; r < 6; ++r) sm += __expf((wmn - hh[r]) / t);
    float S = wave_sum_bcast(sm);
    if (lane == 0) u_sk[m * kN + i] = wmn - t * __logf(S);
}

__global__ __launch_bounds__(64) void sk_col(const float* __restrict__ Call,
                                             const float* __restrict__ CTall, int have_ct,
                                             const float* __restrict__ u_sk,
                                             float* __restrict__ v_sk,
                                             float tau, const float* __restrict__ s) {
    int j = blockIdx.x, m = blockIdx.y, lane = threadIdx.x;
    float t = tau * s[m];
    float hh[6];
    float mn = kInf;
    if (have_ct) {
        const float* R = CTall + (size_t)m * kN * kN + (size_t)j * kN;
        #pragma unroll
        for (int r = 0; r < 6; ++r) {
            int i = lane + 64 * r;
            hh[r] = R[i] - u_sk[m * kN + i];
            mn = fminf(mn, hh[r]);
        }
    } else {
        const float* Cm = Call + (size_t)m * kN * kN;
        #pragma unroll
        for (int r = 0; r < 6; ++r) {
            int i = lane + 64 * r;
            hh[r] = Cm[(size_t)i * kN + j] - u_sk[m * kN + i];
            mn = fminf(mn, hh[r]);
        }
    }
    float wmn = wave_min_bcast(mn);
    float sm = 0.0f;
    #pragma unroll
    for (int r = 0; r < 6; ++r) sm += __expf((wmn - hh[r]) / t);
    float S = wave_sum_bcast(sm);
    if (lane == 0) v_sk[m * kN + j] = wmn - t * __logf(S);
}

// ---- parallel row reduce: u0_i = min_j(C_ij - v_j) + argmin (bitwise) -----
__global__ __launch_bounds__(64) void row_reduce(const float* __restrict__ Call,
                                                 const float* __restrict__ v_sk,
                                                 float* __restrict__ u0,
                                                 int* __restrict__ arg0) {
    int i = blockIdx.x, m = blockIdx.y, lane = threadIdx.x;
    const float* R = Call + (size_t)m * kN * kN + (size_t)i * kN;
    float m1 = kInf; int j1 = 0;
    #pragma unroll
    for (int r = 0; r < 6; ++r) {
        int j = lane + 64 * r;
        float h = R[j] - v_sk[m * kN + j];
        if (h < m1) { m1 = h; j1 = j; }
    }
    float w1 = wave_min_bcast(m1);
    unsigned long long mk = __ballot(m1 == w1);
    int jm = __builtin_amdgcn_readlane(j1, __ffsll(mk) - 1);
    if (lane == 0) { u0[m * kN + i] = w1; arg0[m * kN + i] = jm; }
}

// ---- 384x384 exact JV LAP, one wave per matrix ----------------------------

__global__ __launch_bounds__(64) void lap384(const float* __restrict__ Call,
                                             const float* __restrict__ CTall, int have_ct,
                                             const float* __restrict__ v_init,
                                             const float* __restrict__ u0,
                                             const int* __restrict__ arg0,
                                             const float* __restrict__ Dall,
                                             const float* __restrict__ Iall,
                                             float* __restrict__ loss_out) {
    const int m = blockIdx.x;
    const float* C  = Call  + (size_t)m * kN * kN;
    const float* CT = CTall + (size_t)m * kN * kN;
    const int lane = threadIdx.x;

    __shared__ float u[kN], v[kN];
    __shared__ int xr[kN], yc[kN];
    __shared__ int2 sp[kN];            // (bits of shortest dist, pred row)
    __shared__ int2 steps[kN];         // (pre-augment matched row of col, col)
    __shared__ int2 yu[kN];            // (yc[j], bits of u[yc[j]])
    __shared__ int2 rbatch[kN];        // (row, u_bits), batch-relax only
    __shared__ int flA[kN], flB[kN];
    __shared__ int fcl[kN];
    __shared__ int fc_sh;

    // --- init ---
    for (int j = lane; j < kN; j += 64) {
        v[j] = v_init[m * kN + j];
        xr[j] = -1; yc[j] = -1;
        yu[j] = make_int2(-1, 0);
        u[j] = u0[m * kN + j];
    }
    __syncthreads();

    float vreg[6];
    #pragma unroll
    for (int r = 0; r < 6; ++r) vreg[r] = v[lane + 64 * r];

    // --- parallel greedy claim: row i -> arg0[i] via atomicCAS on yc ---
    int nf = 0;
    #pragma unroll
    for (int r = 0; r < 6; ++r) {
        int i = lane + 64 * r;
        int j1 = arg0[m * kN + i];
        int old = atomicCAS(&yc[j1], -1, i);
        bool won = (old == -1);
        if (won) {
            xr[i] = j1;
            yu[j1] = make_int2(i, __float_as_int(u[i]));
        }
        unsigned long long mk = __ballot(!won);
        int pos = nf + (int)__popcll(mk & ((1ull << lane) - 1ull));
        if (!won) flA[pos] = i;
        nf += (int)__popcll(mk);
    }
    __syncthreads();

    // --- augmenting row reduction, 2 passes, tight-only, cap 2*kN ---
    int* src = flA; int* dst = flB;
    int f0 = nf;
    for (int pass = 0; pass < 2 && f0 > 0; ++pass) {
        int k = 0, f = 0, ops = 0;
        int i = -1;
        bool capped = false;
        for (;;) {
            if (i < 0) {
                if (k >= f0) break;
                i = src[k]; ++k;
            }
            if (++ops > 2 * kN) {
                if (lane == 0) dst[f] = i;
                ++f; capped = true; break;
            }
            const float* Crow = C + (size_t)i * kN;
            float m1 = kInf, m2 = kInf; int j1loc = 0;
            #pragma unroll
            for (int r = 0; r < 6; ++r) {
                int j = lane + 64 * r;
                float hh = Crow[j] - vreg[r];
                if (hh < m1) { m2 = m1; m1 = hh; j1loc = j; }
                else if (hh < m2) { m2 = hh; }
            }
            float w1, w2;
            wave_min2_bcast(m1, m2, w1, w2);
            unsigned long long mk = __ballot(m1 == w1);
            int j1 = __builtin_amdgcn_readlane(j1loc, __ffsll(mk) - 1);
            bool strict = (w1 < w2);
            int i0 = yc[j1];
            if (strict) {
                if (lane == (j1 & 63)) { vreg[j1 >> 6] -= (w2 - w1); v[j1] = vreg[j1 >> 6]; }
                if (lane == 0) {
                    xr[i] = j1; yc[j1] = i; u[i] = w2;
                    yu[j1] = make_int2(i, __float_as_int(w2));
                }
                i = (i0 >= 0) ? i0 : -1;
            } else {
                if (lane == 0) {
                    xr[i] = j1; yc[j1] = i; u[i] = w1;
                    yu[j1] = make_int2(i, __float_as_int(w1));
                }
                if (i0 >= 0) { if (lane == 0) dst[f] = i0; ++f; }
                i = -1;
            }
        }
        if (capped) {
            for (int t = k + lane; t < f0; t += 64) dst[f + (t - k)] = src[t];
            f += f0 - k;
        }
        int* tmp = src; src = dst; dst = tmp;
        f0 = f;
    }
    __syncthreads();

    // --- build free-column list ---
    {
        int fc = 0;
        for (int base = 0; base < kN; base += 64) {
            int j = base + lane;
            bool isfree = (yc[j] < 0);
            unsigned long long mk = __ballot(isfree);
            int pos = fc + __popcll(mk & ((1ull << lane) - 1ull));
            if (isfree) fcl[pos] = j;
            fc += (int)__popcll(mk);
        }
        if (lane == 0) fc_sh = fc;
    }
    __syncthreads();

    // --- shortest augmenting path phases; per-phase free-col dual refresh --
    const int nfree = f0;
    for (int fi = 0; fi < nfree; ++fi) {
        // refresh: v[j] = min_i (C_ij - u_i) for remaining free columns.
        // Only raises free-col v to exact tightness (min over identical
        // exprs) -> dual-feasible, exact; kills the stale-toll wander.
        {
            int fc = fc_sh;
            for (int t = lane; t < fc; t += 64) {
                int j = fcl[t];
                float mn = kInf;
                if (have_ct) {
                    const float4* Rt = (const float4*)(CT + (size_t)j * kN);
                    #pragma unroll 4
                    for (int q = 0; q < kN / 4; ++q) {
                        float4 cv = Rt[q];
                        mn = fminf(mn, cv.x - u[4 * q + 0]);
                        mn = fminf(mn, cv.y - u[4 * q + 1]);
                        mn = fminf(mn, cv.z - u[4 * q + 2]);
                        mn = fminf(mn, cv.w - u[4 * q + 3]);
                    }
                } else {
                    #pragma unroll 4
                    for (int i = 0; i < kN; ++i)
                        mn = fminf(mn, C[(size_t)i * kN + j] - u[i]);
                }
                v[j] = mn;
            }
        }
        __syncthreads();

        const int cur = src[fi];
        float sreg[6];
        unsigned scmask = 0;
        #pragma unroll
        for (int r = 0; r < 6; ++r) { sreg[r] = kInf; vreg[r] = v[lane + 64 * r]; }
        float min_val = 0.0f;
        int sink = -1;
        int scount = 0;
        int nbatch = 1;
        int iters = 0;
        int er = cur;                              // register-carried row
        int eu = __float_as_int(u[cur]);           // and its u-bits
        __syncthreads();

        while (true) {
            // ---- relax ----
            if (nbatch == 1) {                     // registers, no LDS seed
                float b0 = min_val - __int_as_float(eu);
                const float* R = C + (size_t)er * kN;
                float cc[6];
                #pragma unroll
                for (int r = 0; r < 6; ++r) cc[r] = R[lane + 64 * r];
                #pragma unroll
                for (int r = 0; r < 6; ++r) {
                    float d = b0 + cc[r] - vreg[r];
                    bool notsc = ((scmask >> r) & 1u) == 0u;
                    if (notsc && d < sreg[r]) {
                        sreg[r] = d;
                        sp[lane + 64 * r] = make_int2(__float_as_int(d), er);
                    }
                }
            } else {
                for (int t0 = 0; t0 < nbatch; t0 += 4) {
                    int2 e0 = rbatch[t0];
                    int2 e1 = rbatch[(t0 + 1 < nbatch) ? t0 + 1 : nbatch - 1];
                    int2 e2 = rbatch[(t0 + 2 < nbatch) ? t0 + 2 : nbatch - 1];
                    int2 e3 = rbatch[(t0 + 3 < nbatch) ? t0 + 3 : nbatch - 1];
                    float b0 = min_val - __int_as_float(e0.y);
                    float b1 = min_val - __int_as_float(e1.y);
                    float b2 = min_val - __int_as_float(e2.y);
                    float b3 = min_val - __int_as_float(e3.y);
                    const float* R0 = C + (size_t)e0.x * kN;
                    const float* R1 = C + (size_t)e1.x * kN;
                    const float* R2 = C + (size_t)e2.x * kN;
                    const float* R3 = C + (size_t)e3.x * kN;
                    float c0[6], c1[6], c2[6], c3[6];
                    #pragma unroll
                    for (int r = 0; r < 6; ++r) {
                        int j = lane + 64 * r;
                        c0[r] = R0[j]; c1[r] = R1[j]; c2[r] = R2[j]; c3[r] = R3[j];
                    }
                    #pragma unroll
                    for (int r = 0; r < 6; ++r) {
                        float db = sreg[r]; int pred = -1;
                        float d0 = b0 + c0[r] - vreg[r];
                        if (d0 < db) { db = d0; pred = e0.x; }
                        float d1 = b1 + c1[r] - vreg[r];
                        if (d1 < db) { db = d1; pred = e1.x; }
                        float d2 = b2 + c2[r] - vreg[r];
                        if (d2 < db) { db = d2; pred = e2.x; }
                        float d3 = b3 + c3[r] - vreg[r];
                        if (d3 < db) { db = d3; pred = e3.x; }
                        bool notsc = ((scmask >> r) & 1u) == 0u;
                        if (notsc && pred >= 0) {
                            sreg[r] = db;
                            sp[lane + 64 * r] = make_int2(__float_as_int(db), pred);
                        }
                    }
                }
            }

            // ---- global min ----
            float best = fminf(fminf(fminf(sreg[0], sreg[1]), fminf(sreg[2], sreg[3])),
                               fminf(sreg[4], sreg[5]));
            min_val = wave_min_bcast(best);
            if (!(min_val < kInf)) break;            // safety

            // ---- pop: single-ballot fast path, 6-ballot batch fallback ----
            int myreg = -1, hits = 0;
            #pragma unroll
            for (int r = 0; r < 6; ++r) {
                if (sreg[r] == min_val) { if (myreg < 0) myreg = r; ++hits; }
            }
            unsigned long long hmk = __ballot(myreg >= 0);
            int nl = (int)__popcll(hmk);
            int L = __ffsll(hmk) - 1;
            int hcnt = __builtin_amdgcn_readlane(hits, L);
            if (nl == 1 && hcnt == 1) {
                int hreg = __builtin_amdgcn_readlane(myreg, L);
                int bj = L + 64 * hreg;
                if (lane == L) { sreg[hreg] = kInf; scmask |= 1u << hreg; }
                int2 p = yu[bj];                     // broadcast LDS read
                if (lane == 0) steps[scount] = make_int2(p.x, bj);
                ++scount; nbatch = 1;
                er = p.x; eu = p.y;
                if (p.x < 0) sink = bj;
            } else {
                nbatch = 0;
                #pragma unroll
                for (int r = 0; r < 6; ++r) {
                    bool notsc = ((scmask >> r) & 1u) == 0u;
                    bool elig = notsc && (sreg[r] == min_val);
                    unsigned long long mk = __ballot(elig);
                    if (mk == 0) continue;
                    int j = lane + 64 * r;
                    int2 p = make_int2(0, 0);
                    if (elig) { p = yu[j]; sreg[r] = kInf; scmask |= 1u << r; }
                    int pos = (int)__popcll(mk & ((1ull << lane) - 1ull));
                    if (elig) {
                        steps[scount + pos] = make_int2(p.x, j);
                        rbatch[nbatch + pos] = p;
                    }
                    int cnt = (int)__popcll(mk);
                    unsigned long long fmk = __ballot(elig && p.x < 0);
                    if (fmk != 0 && sink < 0) sink = (__ffsll(fmk) - 1) + 64 * r;
                    scount += cnt; nbatch += cnt;
                }
            }
            if (sink >= 0) break;
            if (++iters > kN + 2) break;             // safety
            __syncthreads();
        }

        __syncthreads();
        if (sink >= 0) {
            for (int t = lane; t < scount; t += 64) {
                int2 sij = steps[t];
                int i = sij.x, jc = sij.y;
                float adj = min_val - __int_as_float(sp[jc].x);
                v[jc] -= adj;
                if (i >= 0) u[i] += adj;
            }
            if (lane == 0) u[cur] += min_val;
            __syncthreads();
            if (lane == 0) {
                int j = sink;
                int guard = 0;
                for (;;) {
                    int ii = sp[j].y;
                    yc[j] = ii;
                    int nxt = xr[ii];
                    xr[ii] = j;
                    j = nxt;
                    if (ii == cur) break;
                    if (++guard > kN) break;         // safety
                }
            }
            __syncthreads();
            for (int t = lane; t < scount; t += 64) {
                int jc = steps[t].y;
                int yy = yc[jc];
                yu[jc] = make_int2(yy, (yy >= 0) ? __float_as_int(u[yy]) : 0);
            }
            // remove matched sink from free-column list
            {
                int fcn = fc_sh;
                int hit = -1;
                for (int t = lane; t < fcn; t += 64) if (fcl[t] == sink) hit = t;
                unsigned long long mk = __ballot(hit >= 0);
                if (mk) {
                    if (hit >= 0) fcl[hit] = fcl[fcn - 1];
                    if (lane == __ffsll(mk) - 1) fc_sh = fcn - 1;
                }
            }
            __syncthreads();
        }
    }

    // --- loss = Sum D + Sum I + Sum_i C[i, x[i]] ---
    float s = 0.0f;
    for (int t = lane; t < kN; t += 64) {
        int c_ = xr[t];
        if (c_ >= 0) s += C[(size_t)t * kN + c_];
        s += Dall[m * kN + t] + Iall[m * kN + t];
    }
    #pragma unroll
    for (int off = 32; off > 0; off >>= 1) s += __shfl_down(s, off);
    if (lane == 0) loss_out[m] = s;
}

// ---- finalize -------------------------------------------------------------

__global__ void finalize(const float* __restrict__ loss_sums,
                         const float* __restrict__ score_w,
                         const float* __restrict__ score_b,
                         const float* __restrict__ avg_v,
                         float* __restrict__ out) {
    float mc[3];
    for (int m = 0; m < 3; ++m) mc[m] = 2.0f * (loss_sums[m] / (float)kNN) / (float)kNN;
    float logits = score_b[0];
    for (int m = 0; m < 3; ++m) logits += score_w[m] * mc[m];
    float score = 1.0f / (1.0f + expf(-logits));
    out[0] = score;
    out[1] = -logf(score) * avg_v[0];
    out[2] = mc[0];
    out[3] = mc[1];
    out[4] = mc[2];
}

// ---------------------------------------------------------------------------

extern "C" void kernel_launch(void* const* d_in, const int* in_sizes, int n_in,
                              void* d_out, int out_size, void* d_ws, size_t ws_size,
                              hipStream_t stream) {
    const int*   ei1 = (const int*)d_in[0];
    const int*   ei2 = (const int*)d_in[1];
    const float* x1  = (const float*)d_in[2];
    const float* x2  = (const float*)d_in[3];
    const float* avg = (const float*)d_in[6];

    const float *w[3], *b[3], *dl[3], *insp[3], *score_w, *score_b;
    if (in_sizes[11] == 8192) {  // dict order
        w[0]=(const float*)d_in[7];  b[0]=(const float*)d_in[8];
        dl[0]=(const float*)d_in[9]; insp[0]=(const float*)d_in[10];
        w[1]=(const float*)d_in[11]; b[1]=(const float*)d_in[12];
        dl[1]=(const float*)d_in[13]; insp[1]=(const float*)d_in[14];
        w[2]=(const float*)d_in[15]; b[2]=(const float*)d_in[16];
        dl[2]=(const float*)d_in[17]; insp[2]=(const float*)d_in[18];
        score_w=(const float*)d_in[19]; score_b=(const float*)d_in[20];
    } else {                     // signature order
        w[0]=(const float*)d_in[7];  b[0]=(const float*)d_in[8];
        w[1]=(const float*)d_in[9];  b[1]=(const float*)d_in[10];
        w[2]=(const float*)d_in[11]; b[2]=(const float*)d_in[12];
        dl[0]=(const float*)d_in[13]; dl[1]=(const float*)d_in[14]; dl[2]=(const float*)d_in[15];
        insp[0]=(const float*)d_in[16]; insp[1]=(const float*)d_in[17]; insp[2]=(const float*)d_in[18];
        score_w=(const float*)d_in[19]; score_b=(const float*)d_in[20];
    }

    // Workspace layout (float offsets)
    float* ws = (float*)d_ws;
    float* f1[3]  = { ws + 0,      ws + 49152,  ws + 73728  };
    float* f2[3]  = { ws + 86016,  ws + 135168, ws + 159744 };
    float* h1     = ws + 172032;                                // 384x128
    float* h2     = ws + 221184;                                // 384x128
    float* dinv1  = ws + 270336;
    float* dinv2  = ws + 270720;
    float* Dm     = ws + 271104;                                // 3 x 384
    float* Im     = ws + 272256;                                // 3 x 384
    unsigned* vbits = (unsigned*)(ws + 273408);                 // 3 x 384
    float* C      = ws + 274560;                                // 3 x 384 x 384
    float* loss   = ws + 716928;                                // 3 (+pad)
    float* u_sk   = ws + 716944;                                // 3 x 384
    float* v_sk   = ws + 718096;                                // 3 x 384
    float* s_sk   = ws + 719248;                                // 3 (+pad)
    float* u0     = ws + 719264;                                // 3 x 384
    int*   arg0   = (int*)(ws + 720416);                        // 3 x 384
    float* CT     = ws + 721568;                                // 3 x 384 x 384 (optional)
    const size_t need_ct = (721568 + 3 * (size_t)kN * kN) * sizeof(float);
    const int have_ct = (ws_size >= need_ct) ? 1 : 0;

    init_deg<<<6, 64, 0, stream>>>(dinv1, dinv2);
    scatter_deg<<<24, 256, 0, stream>>>(ei1, ei2, dinv1, dinv2);
    deg_to_dinv<<<6, 64, 0, stream>>>(dinv1, dinv2);

    const int Fs[3] = {128, 64, 32};
    {
        const float* xin1 = x1;
        const float* xin2 = x2;
        int fin = 32, relu = 0;
        for (int li = 0; li < 3; ++li) {
            int OF = Fs[li];
            int nthr = kN * OF;
            gcn_layer<<<dim3((nthr + 255) / 256, 2), 256, 0, stream>>>(
                xin1, xin2, w[li], b[li], dinv1, dinv2, h1, h2, f1[li], f2[li], fin, OF, relu);
            agg_edges2<<<dim3((kE * OF + 255) / 256, 2), 256, 0, stream>>>(
                ei1, ei2, h1, h2, dinv1, dinv2, f1[li], f2[li], OF);
            xin1 = f1[li]; xin2 = f2[li]; fin = OF; relu = 1;
        }
    }

    hipMemsetAsync(vbits, 0, 3 * kN * sizeof(unsigned), stream);  // 0 == bits of +0.0f

    {
        DotJobs dj;
        for (int m = 0; m < 3; ++m) {
            dj.j[m]     = { f1[m], dl[m],   Dm + m * kN, Fs[m] };
            dj.j[3 + m] = { f2[m], insp[m], Im + m * kN, Fs[m] };
        }
        node_dots_all<<<dim3(3, 6), 128, 0, stream>>>(dj);

        CostJobs cj;
        for (int m = 0; m < 3; ++m) {
            cj.j[m] = { f1[m], f2[m], Dm + m * kN, Im + m * kN,
                        C + (size_t)m * kN * kN, CT + (size_t)m * kN * kN,
                        vbits + m * kN, Fs[m] };
        }
        build_cost_all<<<dim3(3, kN, 3), 128, 0, stream>>>(cj, have_ct);
    }

    // Sinkhorn dual warm start: annealed soft row/col reductions (parallel).
    vb2v_scale<<<3, 64, 0, stream>>>(vbits, v_sk, s_sk);
    float tau = 0.8f;
    for (int t = 0; t < 16; ++t) {
        sk_row<<<dim3(kN, 3), 64, 0, stream>>>(C, v_sk, u_sk, tau, s_sk);
        sk_col<<<dim3(kN, 3), 64, 0, stream>>>(C, CT, have_ct, u_sk, v_sk, tau, s_sk);
        tau *= 0.62f;
    }
    // exact parallel row pass: u0 = min_j(C - v), argmin (bitwise-tight)
    row_reduce<<<dim3(kN, 3), 64, 0, stream>>>(C, v_sk, u0, arg0);

    lap384<<<3, 64, 0, stream>>>(C, CT, have_ct, v_sk, u0, arg0, Dm, Im, loss);
    finalize<<<1, 1, 0, stream>>>(loss, score_w, score_b, avg, (float*)d_out);
}